// Round 1
// 244.238 us; speedup vs baseline: 1.1287x; 1.1287x over previous
//
#include <hip/hip_runtime.h>
#include <hip/hip_bf16.h>
#include <stdint.h>

#define B_ 8
#define K_ 2048
#define D_ 1024
#define NC 32
#define TC (K_ / NC)   // 64 timesteps per chunk

typedef float v4f __attribute__((ext_vector_type(4)));
typedef short v8s __attribute__((ext_vector_type(8)));

__device__ __forceinline__ unsigned short f2bf(float f) {
    __hip_bfloat16 h = __float2bfloat16(f);
    return *reinterpret_cast<unsigned short*>(&h);
}

__device__ __forceinline__ void async_ld16(const void* g, void* l) {
    __builtin_amdgcn_global_load_lds(
        (__attribute__((address_space(1))) void*)(void*)g,
        (__attribute__((address_space(3))) void*)l,
        16, 0, 0);
}

// ---------------- converter: W (fp32 [K][K]) -> bf16 [K][K] ----------------
__global__ void conv_w(const float* __restrict__ W, unsigned short* __restrict__ Wb) {
    int i = (blockIdx.x * 256 + threadIdx.x) * 4;
    float4 v = *(const float4*)(W + i);
    ushort4 o;
    o.x = f2bf(v.x); o.y = f2bf(v.y); o.z = f2bf(v.z); o.w = f2bf(v.w);
    *(ushort4*)(Wb + i) = o;
}

// ---------- converter+transpose: x fp32 [B][K][D] -> xT bf16 [B][D][K] ----------
__global__ void conv_x_t(const float* __restrict__ x, unsigned short* __restrict__ xT) {
    const int k0 = blockIdx.x * 64, d0 = blockIdx.y * 64, bb = blockIdx.z;
    __shared__ unsigned short tile[64][68];   // pad 68 to break bank alignment
    const int tid = threadIdx.x;
    const int tx = tid & 15, ty = tid >> 4;
    const float* xp = x + (size_t)bb * K_ * D_;
#pragma unroll
    for (int r = 0; r < 4; r++) {
        int row = ty + r * 16;
        float4 v = *(const float4*)(xp + (size_t)(k0 + row) * D_ + d0 + tx * 4);
        tile[row][tx * 4 + 0] = f2bf(v.x);
        tile[row][tx * 4 + 1] = f2bf(v.y);
        tile[row][tx * 4 + 2] = f2bf(v.z);
        tile[row][tx * 4 + 3] = f2bf(v.w);
    }
    __syncthreads();
    unsigned short* op = xT + (size_t)bb * D_ * K_;
#pragma unroll
    for (int r = 0; r < 4; r++) {
        int dcol = ty + r * 16;
        ushort4 u;
        u.x = tile[tx * 4 + 0][dcol];
        u.y = tile[tx * 4 + 1][dcol];
        u.z = tile[tx * 4 + 2][dcol];
        u.w = tile[tx * 4 + 3][dcol];
        *(ushort4*)(op + (size_t)(d0 + dcol) * K_ + k0 + tx * 4) = u;
    }
}

// ---------------- GEMM + bias + sigmoid: lam[b][t][d] ----------------
// 256x256 tile, 8 waves (2M x 4N), per-wave output 128x64, BK=64 split as two
// k-halves (kh=0,1) of 32. LDS = 2 K-tile double buffer x 2 kh x [256 rows][32 hw]
// per operand = 128 KiB total. Schedule: 4 phases per K-tile
// (quadrants: {kh0,j01} {kh0,j23} {kh1,j01} {kh1,j23}); each phase stages ONE
// half-tile of K-tile t+1 into the OTHER buffer (so in-flight loads never touch
// the buffer being read -> no WAR race), with raw s_barrier (no compiler
// vmcnt(0) drain) and counted s_waitcnt vmcnt(4) only at even-phase ends:
//   at ph2-end the per-wave VMEM queue is [tA1,tB1,(t+1)A0,(t+1)B0] -> vmcnt(4)
//   guarantees tile-t kh1 resident for ph3; at ph4-end the queue is tile t+1's
//   4 halves -> vmcnt(4) guarantees its kh0 for the next group's ph1.
// Every staged half gets ~4 phases (~600+ cyc) of latency cover.
// LDS bank swizzle: granule slot = gk ^ ((row>>1)&3) applied identically on the
// per-lane GLOBAL source address (gload_lds dest stays lane-linear, rule #21)
// and on the ds_read_b128 address -> 16 same-quad lanes spread over all 8
// 16B bank slots (2-way residual, free).
__launch_bounds__(512, 2)
__global__ void gemm_sig(const unsigned short* __restrict__ Wb,
                         const unsigned short* __restrict__ xT,
                         const float* __restrict__ bias,
                         float* __restrict__ lam) {
    __shared__ unsigned short As[2][2][256 * 32];
    __shared__ unsigned short Bs[2][2][256 * 32];

    // XCD-chunked bijective swizzle (nwg=256): XCD r owns logical ids [r*32,r*32+32)
    // -> one batch b per XCD; xT[b] (4 MB) ~ fits the XCD-private L2.
    const int bid = blockIdx.x;
    const int lid = (bid & 7) * 32 + (bid >> 3);
    const int bb = lid >> 5;          // batch
    const int tM = (lid >> 2) & 7;    // 8 M-tiles
    const int tN = lid & 3;           // 4 N-tiles

    const int tid = threadIdx.x;
    const int w = tid >> 6;           // wave 0..7
    const int lane = tid & 63;
    const int wm = w >> 2;            // 0..1  (M)
    const int wn = w & 3;             // 0..3  (N)
    const int quad = lane >> 4;
    const int l16 = lane & 15;

    const unsigned short* Ag = Wb + (size_t)(tM * 256) * K_;
    const unsigned short* Bg = xT + (size_t)bb * D_ * K_ + (size_t)(tN * 256) * K_;

    // staging lane constants: 1KB LDS block = 16 rows x 4 granules (16B each);
    // lane l -> row_in_block = l>>2, holds granule gk = (l&3) ^ ((l>>3)&3)
    // so that LDS slot (l&3) == gk ^ ((row>>1)&3).
    const int srow = lane >> 2;
    const int sgk8 = ((lane & 3) ^ ((lane >> 3) & 3)) * 8;   // halfword offset

    // fragment ds_read offsets (halfwords): row*32 + (quad ^ ((row>>1)&3))*8;
    // (row>>1)&3 reduces to (l16>>1)&3 since all row bases are multiples of 8.
    const int frg = (quad ^ ((l16 >> 1) & 3)) * 8;
    const int aoff = (wm * 128 + l16) * 32 + frg;
    const int boff = (wn * 64 + l16) * 32 + frg;

    v4f acc[8][4];
#pragma unroll
    for (int i = 0; i < 8; i++)
#pragma unroll
        for (int j = 0; j < 4; j++) acc[i][j] = (v4f)0.f;

    // stage one half-tile [256 rows][32 k] = 16 blocks; wave w takes blocks w, w+8
#define STAGE_(dst, bufi, kh, kk, Gp)                                                   \
    do {                                                                                \
        async_ld16(Gp + (size_t)(w * 16 + srow) * K_ + (kk) + (kh) * 32 + sgk8,         \
                   &dst[bufi][kh][w * 512]);                                            \
        async_ld16(Gp + (size_t)((8 + w) * 16 + srow) * K_ + (kk) + (kh) * 32 + sgk8,   \
                   &dst[bufi][kh][(8 + w) * 512]);                                      \
    } while (0)

    // prologue: tile 0's 4 halves; leave kh1 pair in flight (steady-state invariant)
    STAGE_(As, 0, 0, 0, Ag);
    STAGE_(Bs, 0, 0, 0, Bg);
    STAGE_(As, 0, 1, 0, Ag);
    STAGE_(Bs, 0, 1, 0, Bg);
    asm volatile("s_waitcnt vmcnt(4)");
    asm volatile("s_barrier" ::: "memory");

    v8s af[8], bf[2];

    for (int t = 0; t < K_ / 64; ++t) {
        const int cur = t & 1, nxt = cur ^ 1;
        int k1 = (t + 1) * 64;
        if (k1 == K_) k1 = 0;   // last group re-stages tile 0 (harmless, keeps counts uniform)

        // ---------------- phase 1: kh0, j01 ----------------
#pragma unroll
        for (int i = 0; i < 8; i++) af[i] = *(const v8s*)(&As[cur][0][aoff + i * 512]);
        bf[0] = *(const v8s*)(&Bs[cur][0][boff]);
        bf[1] = *(const v8s*)(&Bs[cur][0][boff + 512]);
        STAGE_(As, nxt, 0, k1, Ag);
        asm volatile("s_barrier" ::: "memory");
        asm volatile("s_waitcnt lgkmcnt(0)");
        __builtin_amdgcn_s_setprio(1);
#pragma unroll
        for (int i = 0; i < 8; i++) {
            acc[i][0] = __builtin_amdgcn_mfma_f32_16x16x32_bf16(af[i], bf[0], acc[i][0], 0, 0, 0);
            acc[i][1] = __builtin_amdgcn_mfma_f32_16x16x32_bf16(af[i], bf[1], acc[i][1], 0, 0, 0);
        }
        __builtin_amdgcn_s_setprio(0);
        asm volatile("s_barrier" ::: "memory");

        // ---------------- phase 2: kh0, j23 ----------------
        bf[0] = *(const v8s*)(&Bs[cur][0][boff + 2 * 512]);
        bf[1] = *(const v8s*)(&Bs[cur][0][boff + 3 * 512]);
        STAGE_(Bs, nxt, 0, k1, Bg);
        asm volatile("s_barrier" ::: "memory");
        asm volatile("s_waitcnt lgkmcnt(0)");
        __builtin_amdgcn_s_setprio(1);
#pragma unroll
        for (int i = 0; i < 8; i++) {
            acc[i][2] = __builtin_amdgcn_mfma_f32_16x16x32_bf16(af[i], bf[0], acc[i][2], 0, 0, 0);
            acc[i][3] = __builtin_amdgcn_mfma_f32_16x16x32_bf16(af[i], bf[1], acc[i][3], 0, 0, 0);
        }
        __builtin_amdgcn_s_setprio(0);
        asm volatile("s_waitcnt vmcnt(4)");   // tile-t kh1 halves now resident
        asm volatile("s_barrier" ::: "memory");

        // ---------------- phase 3: kh1, j01 ----------------
#pragma unroll
        for (int i = 0; i < 8; i++) af[i] = *(const v8s*)(&As[cur][1][aoff + i * 512]);
        bf[0] = *(const v8s*)(&Bs[cur][1][boff]);
        bf[1] = *(const v8s*)(&Bs[cur][1][boff + 512]);
        STAGE_(As, nxt, 1, k1, Ag);
        asm volatile("s_barrier" ::: "memory");
        asm volatile("s_waitcnt lgkmcnt(0)");
        __builtin_amdgcn_s_setprio(1);
#pragma unroll
        for (int i = 0; i < 8; i++) {
            acc[i][0] = __builtin_amdgcn_mfma_f32_16x16x32_bf16(af[i], bf[0], acc[i][0], 0, 0, 0);
            acc[i][1] = __builtin_amdgcn_mfma_f32_16x16x32_bf16(af[i], bf[1], acc[i][1], 0, 0, 0);
        }
        __builtin_amdgcn_s_setprio(0);
        asm volatile("s_barrier" ::: "memory");

        // ---------------- phase 4: kh1, j23 ----------------
        bf[0] = *(const v8s*)(&Bs[cur][1][boff + 2 * 512]);
        bf[1] = *(const v8s*)(&Bs[cur][1][boff + 3 * 512]);
        STAGE_(Bs, nxt, 1, k1, Bg);
        asm volatile("s_barrier" ::: "memory");
        asm volatile("s_waitcnt lgkmcnt(0)");
        __builtin_amdgcn_s_setprio(1);
#pragma unroll
        for (int i = 0; i < 8; i++) {
            acc[i][2] = __builtin_amdgcn_mfma_f32_16x16x32_bf16(af[i], bf[0], acc[i][2], 0, 0, 0);
            acc[i][3] = __builtin_amdgcn_mfma_f32_16x16x32_bf16(af[i], bf[1], acc[i][3], 0, 0, 0);
        }
        __builtin_amdgcn_s_setprio(0);
        asm volatile("s_waitcnt vmcnt(4)");   // tile-(t+1) kh0 halves now resident
        asm volatile("s_barrier" ::: "memory");
    }
#undef STAGE_

    // epilogue: bias + sigmoid, C/D map col=l16, row=quad*4+r (16x16x32 layout)
    float* out = lam + (size_t)bb * K_ * D_;
#pragma unroll
    for (int i = 0; i < 8; i++) {
        int rowb = tM * 256 + wm * 128 + i * 16 + quad * 4;
#pragma unroll
        for (int r = 0; r < 4; r++) {
            float bt = bias[rowb + r];
#pragma unroll
            for (int j = 0; j < 4; j++) {
                int col = tN * 256 + wn * 64 + j * 16 + l16;
                float v = acc[i][j][r] + bt;
                out[(size_t)(rowb + r) * D_ + col] = 1.f / (1.f + __expf(-v));
            }
        }
    }
}

// -------- scan pass 1: per-(b,chunk,d2) affine composition (A,U), float2/lane --------
__global__ void scan_pass1(const float* __restrict__ lam, const float* __restrict__ x,
                           float* __restrict__ Ac, float* __restrict__ Uc) {
    int id = blockIdx.x * 256 + threadIdx.x;   // B*NC*D/2 = 131072
    int d2 = (id & 511) * 2;
    int c = (id >> 9) & (NC - 1);
    int bb = id >> 14;
    const float* lp = lam + ((size_t)bb * K_ + (size_t)c * TC) * D_ + d2;
    const float* xp = x   + ((size_t)bb * K_ + (size_t)c * TC) * D_ + d2;
    float2 A = make_float2(1.f, 1.f), U = make_float2(0.f, 0.f);
#pragma unroll 8
    for (int t = 0; t < TC; t++) {
        float2 l  = *(const float2*)(lp + (size_t)t * D_);
        float2 xv = *(const float2*)(xp + (size_t)t * D_);
        A.x *= l.x; A.y *= l.y;
        U.x = l.x * U.x + (1.f - l.x) * xv.x;
        U.y = l.y * U.y + (1.f - l.y) * xv.y;
    }
    size_t oi = ((size_t)bb * NC + c) * D_ + d2;
    *(float2*)(Ac + oi) = A;
    *(float2*)(Uc + oi) = U;
}

// -------- scan pass 2: chunk-level exclusive prefix (entry state per chunk) --------
__global__ void scan_pass2(const float* __restrict__ Ac, const float* __restrict__ Uc,
                           float* __restrict__ Sin) {
    int id = blockIdx.x * 256 + threadIdx.x;   // B*D = 8192
    int d = id & (D_ - 1);
    int bb = id >> 10;
    float s = 0.f;
#pragma unroll
    for (int c = 0; c < NC; c++) {
        int idx = (bb * NC + c) * D_ + d;
        Sin[idx] = s;
        s = Ac[idx] * s + Uc[idx];
    }
}

// -------- scan pass 3: replay chunk with entry state, float2/lane, in-place over lam --------
__global__ void scan_pass3(const float* __restrict__ x, const float* __restrict__ Sin,
                           float* __restrict__ lamout) {
    int id = blockIdx.x * 256 + threadIdx.x;   // 131072
    int d2 = (id & 511) * 2;
    int c = (id >> 9) & (NC - 1);
    int bb = id >> 14;
    float* lp = lamout + ((size_t)bb * K_ + (size_t)c * TC) * D_ + d2;
    const float* xp = x + ((size_t)bb * K_ + (size_t)c * TC) * D_ + d2;
    size_t si = ((size_t)bb * NC + c) * D_ + d2;
    float2 s = *(const float2*)(Sin + si);
#pragma unroll 8
    for (int t = 0; t < TC; t++) {
        float2 l  = *(const float2*)(lp + (size_t)t * D_);
        float2 xv = *(const float2*)(xp + (size_t)t * D_);
        s.x = l.x * s.x + (1.f - l.x) * xv.x;
        s.y = l.y * s.y + (1.f - l.y) * xv.y;
        *(float2*)(lp + (size_t)t * D_) = s;   // read-before-write, same thread
    }
}

extern "C" void kernel_launch(void* const* d_in, const int* in_sizes, int n_in,
                              void* d_out, int out_size, void* d_ws, size_t ws_size,
                              hipStream_t stream) {
    const float* x    = (const float*)d_in[0];
    const float* W    = (const float*)d_in[1];
    const float* bias = (const float*)d_in[2];
    float* out = (float*)d_out;
    char* ws = (char*)d_ws;

    unsigned short* xT = (unsigned short*)ws;                       // 32 MiB  [B][D][K] bf16
    unsigned short* Wb = (unsigned short*)(ws + 33554432);          // 8 MiB   [K][K] bf16
    // Ac/Uc/Sin (1 MiB each) overlay Wb's region — Wb is dead once gemm_sig completes.
    float* Ac  = (float*)(ws + 33554432);
    float* Uc  = (float*)(ws + 33554432 + 1048576);
    float* Sin = (float*)(ws + 33554432 + 2097152);

    conv_w<<<dim3(K_ * K_ / 4 / 256), 256, 0, stream>>>(W, Wb);
    conv_x_t<<<dim3(K_ / 64, D_ / 64, B_), 256, 0, stream>>>(x, xT);
    // lam goes into d_out; pass3 overwrites it in place with the final scan output
    gemm_sig<<<dim3(256), dim3(512), 0, stream>>>(Wb, xT, bias, out);
    scan_pass1<<<dim3(B_ * NC * D_ / 2 / 256), 256, 0, stream>>>(out, x, Ac, Uc);
    scan_pass2<<<dim3(B_ * D_ / 256), 256, 0, stream>>>(Ac, Uc, Sin);
    scan_pass3<<<dim3(B_ * NC * D_ / 2 / 256), 256, 0, stream>>>(x, Sin, out);
}

// Round 2
// 237.465 us; speedup vs baseline: 1.1609x; 1.0285x over previous
//
#include <hip/hip_runtime.h>
#include <hip/hip_bf16.h>
#include <stdint.h>

#define B_ 8
#define K_ 2048
#define D_ 1024
#define NC 32
#define TC (K_ / NC)   // 64 timesteps per chunk

typedef float v4f __attribute__((ext_vector_type(4)));
typedef short v8s __attribute__((ext_vector_type(8)));

__device__ __forceinline__ unsigned short f2bf(float f) {
    __hip_bfloat16 h = __float2bfloat16(f);
    return *reinterpret_cast<unsigned short*>(&h);
}

__device__ __forceinline__ void async_ld16(const void* g, void* l) {
    __builtin_amdgcn_global_load_lds(
        (__attribute__((address_space(1))) void*)(void*)g,
        (__attribute__((address_space(3))) void*)l,
        16, 0, 0);
}

// ---------------- converter: W (fp32 [K][K]) -> bf16 [K][K] ----------------
__global__ void conv_w(const float* __restrict__ W, unsigned short* __restrict__ Wb) {
    int i = (blockIdx.x * 256 + threadIdx.x) * 4;
    float4 v = *(const float4*)(W + i);
    ushort4 o;
    o.x = f2bf(v.x); o.y = f2bf(v.y); o.z = f2bf(v.z); o.w = f2bf(v.w);
    *(ushort4*)(Wb + i) = o;
}

// ---------- converter+transpose: x fp32 [B][K][D] -> xT bf16 [B][D][K] ----------
__global__ void conv_x_t(const float* __restrict__ x, unsigned short* __restrict__ xT) {
    const int k0 = blockIdx.x * 64, d0 = blockIdx.y * 64, bb = blockIdx.z;
    __shared__ unsigned short tile[64][68];   // pad 68 to break bank alignment
    const int tid = threadIdx.x;
    const int tx = tid & 15, ty = tid >> 4;
    const float* xp = x + (size_t)bb * K_ * D_;
#pragma unroll
    for (int r = 0; r < 4; r++) {
        int row = ty + r * 16;
        float4 v = *(const float4*)(xp + (size_t)(k0 + row) * D_ + d0 + tx * 4);
        tile[row][tx * 4 + 0] = f2bf(v.x);
        tile[row][tx * 4 + 1] = f2bf(v.y);
        tile[row][tx * 4 + 2] = f2bf(v.z);
        tile[row][tx * 4 + 3] = f2bf(v.w);
    }
    __syncthreads();
    unsigned short* op = xT + (size_t)bb * D_ * K_;
#pragma unroll
    for (int r = 0; r < 4; r++) {
        int dcol = ty + r * 16;
        ushort4 u;
        u.x = tile[tx * 4 + 0][dcol];
        u.y = tile[tx * 4 + 1][dcol];
        u.z = tile[tx * 4 + 2][dcol];
        u.w = tile[tx * 4 + 3][dcol];
        *(ushort4*)(op + (size_t)(d0 + dcol) * K_ + k0 + tx * 4) = u;
    }
}

// ---------------- GEMM + bias + sigmoid (+ fused chunk-scan pass1) ----------------
// 256x256 tile, 8 waves (2M x 4N), 4-phase K-loop with counted vmcnt(4) and
// LDS XOR swizzle (see R1 comments; bank conflicts measured 0, FETCH near-ideal).
// NEW: each WG tile covers exactly 4 complete time-chunks (TC=64) x 256 d-cols,
// so per-chunk (A,U) = (prod lam, scan) is computed in the epilogue:
//   per wave: sigmoid(acc+bias) -> global lam AND a wave-private 64x64 f32 LDS
//   scratch (XOR-swizzled: col' = col ^ quad*16 on write, lane ^ ((t>>2)&3)*16 on
//   read -> 2 lanes/bank both ways = free), then a 64-step sequential scan per
//   lane-column reading x f32 straight from global (coalesced 256B/wave/step,
//   each x element read exactly once chip-wide). Removes scan_pass1 entirely
//   (-128 MB of lam+x re-reads + a launch).
// Hazards handled:
//  - last K-iter prefetch lands in LDS async -> vmcnt(0)+s_barrier before the
//    scratch region (which aliases As/Bs) is overwritten.
//  - Ac/Uc must NOT overlay Wb (other WGs still read Wb while this WG's epilogue
//    writes) -> fused path uses fresh ws after Wb, gated on ws_size at launch;
//    fallback (fuse=0) runs the old separate scan_pass1.
__launch_bounds__(512, 2)
__global__ void gemm_sig(const unsigned short* __restrict__ Wb,
                         const unsigned short* __restrict__ xT,
                         const float* __restrict__ bias,
                         const float* __restrict__ xf,
                         float* __restrict__ lam,
                         float* __restrict__ Ac,
                         float* __restrict__ Uc,
                         int fuse) {
    // [op][buf][kh][256 rows * 32 hw] : op0=A(W), op1=B(xT). 128 KiB total.
    __shared__ __align__(16) unsigned short smem_all[2][2][2][256 * 32];

    // XCD-chunked bijective swizzle (nwg=256): one batch b per XCD -> xT[b] ~ L2.
    const int bid = blockIdx.x;
    const int lid = (bid & 7) * 32 + (bid >> 3);
    const int bb = lid >> 5;          // batch
    const int tM = (lid >> 2) & 7;    // 8 M-tiles
    const int tN = lid & 3;           // 4 N-tiles

    const int tid = threadIdx.x;
    const int w = tid >> 6;           // wave 0..7
    const int lane = tid & 63;
    const int wm = w >> 2;            // 0..1  (M)
    const int wn = w & 3;             // 0..3  (N)
    const int quad = lane >> 4;
    const int l16 = lane & 15;

    const unsigned short* Ag = Wb + (size_t)(tM * 256) * K_;
    const unsigned short* Bg = xT + (size_t)bb * D_ * K_ + (size_t)(tN * 256) * K_;

    // staging lane constants: 1KB LDS block = 16 rows x 4 granules (16B each);
    // lane l holds granule gk = (l&3) ^ ((l>>3)&3) so LDS slot matches the
    // ds_read-side XOR (rule #21: gload_lds dest stays lane-linear; swizzle the
    // global source + the read address with the same involution).
    const int srow = lane >> 2;
    const int sgk8 = ((lane & 3) ^ ((lane >> 3) & 3)) * 8;   // halfword offset

    const int frg = (quad ^ ((l16 >> 1) & 3)) * 8;
    const int aoff = (wm * 128 + l16) * 32 + frg;
    const int boff = (wn * 64 + l16) * 32 + frg;

    v4f acc[8][4];
#pragma unroll
    for (int i = 0; i < 8; i++)
#pragma unroll
        for (int j = 0; j < 4; j++) acc[i][j] = (v4f)0.f;

#define STAGE_(op, bufi, kh, kk, Gp)                                                        \
    do {                                                                                    \
        async_ld16(Gp + (size_t)(w * 16 + srow) * K_ + (kk) + (kh) * 32 + sgk8,             \
                   &smem_all[op][bufi][kh][w * 512]);                                       \
        async_ld16(Gp + (size_t)((8 + w) * 16 + srow) * K_ + (kk) + (kh) * 32 + sgk8,       \
                   &smem_all[op][bufi][kh][(8 + w) * 512]);                                 \
    } while (0)

    // prologue: tile 0's 4 halves
    STAGE_(0, 0, 0, 0, Ag);
    STAGE_(1, 0, 0, 0, Bg);
    STAGE_(0, 0, 1, 0, Ag);
    STAGE_(1, 0, 1, 0, Bg);
    asm volatile("s_waitcnt vmcnt(4)");
    asm volatile("s_barrier" ::: "memory");

    v8s af[8], bf[2];

    for (int t = 0; t < K_ / 64; ++t) {
        const int cur = t & 1, nxt = cur ^ 1;
        int k1 = (t + 1) * 64;
        if (k1 == K_) k1 = 0;   // last group re-stages tile 0 (drained before epilogue)

        // ---------------- phase 1: kh0, j01 ----------------
#pragma unroll
        for (int i = 0; i < 8; i++) af[i] = *(const v8s*)(&smem_all[0][cur][0][aoff + i * 512]);
        bf[0] = *(const v8s*)(&smem_all[1][cur][0][boff]);
        bf[1] = *(const v8s*)(&smem_all[1][cur][0][boff + 512]);
        STAGE_(0, nxt, 0, k1, Ag);
        asm volatile("s_barrier" ::: "memory");
        asm volatile("s_waitcnt lgkmcnt(0)");
        __builtin_amdgcn_sched_barrier(0);
        __builtin_amdgcn_s_setprio(1);
#pragma unroll
        for (int i = 0; i < 8; i++) {
            acc[i][0] = __builtin_amdgcn_mfma_f32_16x16x32_bf16(af[i], bf[0], acc[i][0], 0, 0, 0);
            acc[i][1] = __builtin_amdgcn_mfma_f32_16x16x32_bf16(af[i], bf[1], acc[i][1], 0, 0, 0);
        }
        __builtin_amdgcn_s_setprio(0);
        asm volatile("s_barrier" ::: "memory");

        // ---------------- phase 2: kh0, j23 ----------------
        bf[0] = *(const v8s*)(&smem_all[1][cur][0][boff + 2 * 512]);
        bf[1] = *(const v8s*)(&smem_all[1][cur][0][boff + 3 * 512]);
        STAGE_(1, nxt, 0, k1, Bg);
        asm volatile("s_barrier" ::: "memory");
        asm volatile("s_waitcnt lgkmcnt(0)");
        __builtin_amdgcn_sched_barrier(0);
        __builtin_amdgcn_s_setprio(1);
#pragma unroll
        for (int i = 0; i < 8; i++) {
            acc[i][2] = __builtin_amdgcn_mfma_f32_16x16x32_bf16(af[i], bf[0], acc[i][2], 0, 0, 0);
            acc[i][3] = __builtin_amdgcn_mfma_f32_16x16x32_bf16(af[i], bf[1], acc[i][3], 0, 0, 0);
        }
        __builtin_amdgcn_s_setprio(0);
        asm volatile("s_waitcnt vmcnt(4)");   // tile-t kh1 halves now resident
        asm volatile("s_barrier" ::: "memory");

        // ---------------- phase 3: kh1, j01 ----------------
#pragma unroll
        for (int i = 0; i < 8; i++) af[i] = *(const v8s*)(&smem_all[0][cur][1][aoff + i * 512]);
        bf[0] = *(const v8s*)(&smem_all[1][cur][1][boff]);
        bf[1] = *(const v8s*)(&smem_all[1][cur][1][boff + 512]);
        STAGE_(0, nxt, 1, k1, Ag);
        asm volatile("s_barrier" ::: "memory");
        asm volatile("s_waitcnt lgkmcnt(0)");
        __builtin_amdgcn_sched_barrier(0);
        __builtin_amdgcn_s_setprio(1);
#pragma unroll
        for (int i = 0; i < 8; i++) {
            acc[i][0] = __builtin_amdgcn_mfma_f32_16x16x32_bf16(af[i], bf[0], acc[i][0], 0, 0, 0);
            acc[i][1] = __builtin_amdgcn_mfma_f32_16x16x32_bf16(af[i], bf[1], acc[i][1], 0, 0, 0);
        }
        __builtin_amdgcn_s_setprio(0);
        asm volatile("s_barrier" ::: "memory");

        // ---------------- phase 4: kh1, j23 ----------------
        bf[0] = *(const v8s*)(&smem_all[1][cur][1][boff + 2 * 512]);
        bf[1] = *(const v8s*)(&smem_all[1][cur][1][boff + 3 * 512]);
        STAGE_(1, nxt, 1, k1, Bg);
        asm volatile("s_barrier" ::: "memory");
        asm volatile("s_waitcnt lgkmcnt(0)");
        __builtin_amdgcn_sched_barrier(0);
        __builtin_amdgcn_s_setprio(1);
#pragma unroll
        for (int i = 0; i < 8; i++) {
            acc[i][2] = __builtin_amdgcn_mfma_f32_16x16x32_bf16(af[i], bf[0], acc[i][2], 0, 0, 0);
            acc[i][3] = __builtin_amdgcn_mfma_f32_16x16x32_bf16(af[i], bf[1], acc[i][3], 0, 0, 0);
        }
        __builtin_amdgcn_s_setprio(0);
        asm volatile("s_waitcnt vmcnt(4)");   // tile-(t+1) kh0 halves now resident
        asm volatile("s_barrier" ::: "memory");
    }
#undef STAGE_

    // drain in-flight prefetch (last iter staged into LDS) before scratch reuse
    asm volatile("s_waitcnt vmcnt(0)");
    asm volatile("s_barrier" ::: "memory");

    float* out = lam + (size_t)bb * K_ * D_;
    const int dg = tN * 256 + wn * 64;       // wave col base in d

    if (fuse) {
        // wave-private 64x64 f32 scratch (16 KiB each, 8 waves = 128 KiB = all LDS)
        float* Swp = (float*)smem_all + w * 4096;
        const int swzw = quad * 16;          // write-side XOR: ((R>>2)&3)*16 == quad*16
#pragma unroll
        for (int cg = 0; cg < 2; cg++) {
            const int c = tM * 4 + wm * 2 + cg;   // global chunk id
            const int t0 = c * 64;
#pragma unroll
            for (int ii = 0; ii < 4; ii++) {
                int i = cg * 4 + ii;
                int rowb = t0 + ii * 16 + quad * 4;   // global t row base
                int Rb = ii * 16 + quad * 4;          // row within chunk
#pragma unroll
                for (int r = 0; r < 4; r++) {
                    float bt = bias[rowb + r];
#pragma unroll
                    for (int j = 0; j < 4; j++) {
                        int colc = j * 16 + l16;
                        float v = acc[i][j][r] + bt;
                        float sg = 1.f / (1.f + __expf(-v));
                        out[(size_t)(rowb + r) * D_ + dg + colc] = sg;
                        Swp[(Rb + r) * 64 + (colc ^ swzw)] = sg;
                    }
                }
            }
            asm volatile("s_waitcnt lgkmcnt(0)");
            __builtin_amdgcn_sched_barrier(0);
            // sequential chunk scan: lane owns column d = dg + lane
            const float* xg = xf + ((size_t)bb * K_ + t0) * D_ + dg + lane;
            float A = 1.f, U = 0.f;
#pragma unroll 8
            for (int tt = 0; tt < 64; tt++) {
                float l = Swp[tt * 64 + (lane ^ (((tt >> 2) & 3) * 16))];
                float xv = xg[(size_t)tt * D_];
                A *= l;
                U = l * U + (1.f - l) * xv;
            }
            size_t oi = ((size_t)bb * NC + c) * D_ + dg + lane;
            Ac[oi] = A;
            Uc[oi] = U;
            __builtin_amdgcn_sched_barrier(0);   // keep cg=1 writes below cg=0 reads
        }
    } else {
        // plain epilogue (fallback when ws too small for fused Ac/Uc placement)
#pragma unroll
        for (int i = 0; i < 8; i++) {
            int rowb = tM * 256 + wm * 128 + i * 16 + quad * 4;
#pragma unroll
            for (int r = 0; r < 4; r++) {
                float bt = bias[rowb + r];
#pragma unroll
                for (int j = 0; j < 4; j++) {
                    int col = tN * 256 + wn * 64 + j * 16 + l16;
                    float v = acc[i][j][r] + bt;
                    out[(size_t)(rowb + r) * D_ + col] = 1.f / (1.f + __expf(-v));
                }
            }
        }
    }
}

// -------- scan pass 1 (FALLBACK ONLY): per-(b,chunk,d2) affine composition --------
__global__ void scan_pass1(const float* __restrict__ lam, const float* __restrict__ x,
                           float* __restrict__ Ac, float* __restrict__ Uc) {
    int id = blockIdx.x * 256 + threadIdx.x;   // B*NC*D/2 = 131072
    int d2 = (id & 511) * 2;
    int c = (id >> 9) & (NC - 1);
    int bb = id >> 14;
    const float* lp = lam + ((size_t)bb * K_ + (size_t)c * TC) * D_ + d2;
    const float* xp = x   + ((size_t)bb * K_ + (size_t)c * TC) * D_ + d2;
    float2 A = make_float2(1.f, 1.f), U = make_float2(0.f, 0.f);
#pragma unroll 8
    for (int t = 0; t < TC; t++) {
        float2 l  = *(const float2*)(lp + (size_t)t * D_);
        float2 xv = *(const float2*)(xp + (size_t)t * D_);
        A.x *= l.x; A.y *= l.y;
        U.x = l.x * U.x + (1.f - l.x) * xv.x;
        U.y = l.y * U.y + (1.f - l.y) * xv.y;
    }
    size_t oi = ((size_t)bb * NC + c) * D_ + d2;
    *(float2*)(Ac + oi) = A;
    *(float2*)(Uc + oi) = U;
}

// -------- scan pass 2: chunk-level exclusive prefix (entry state per chunk) --------
// 64-thread blocks: 128 blocks -> spreads this latency-bound kernel over 128 CUs
// (was 32 blocks of 256 = only 32 CUs busy).
__global__ void scan_pass2(const float* __restrict__ Ac, const float* __restrict__ Uc,
                           float* __restrict__ Sin) {
    int id = blockIdx.x * 64 + threadIdx.x;   // B*D = 8192
    int d = id & (D_ - 1);
    int bb = id >> 10;
    float s = 0.f;
#pragma unroll
    for (int c = 0; c < NC; c++) {
        int idx = (bb * NC + c) * D_ + d;
        Sin[idx] = s;
        s = Ac[idx] * s + Uc[idx];
    }
}

// -------- scan pass 3: replay chunk with entry state, float2/lane, in-place over lam --------
__global__ void scan_pass3(const float* __restrict__ x, const float* __restrict__ Sin,
                           float* __restrict__ lamout) {
    int id = blockIdx.x * 256 + threadIdx.x;   // 131072
    int d2 = (id & 511) * 2;
    int c = (id >> 9) & (NC - 1);
    int bb = id >> 14;
    float* lp = lamout + ((size_t)bb * K_ + (size_t)c * TC) * D_ + d2;
    const float* xp = x + ((size_t)bb * K_ + (size_t)c * TC) * D_ + d2;
    size_t si = ((size_t)bb * NC + c) * D_ + d2;
    float2 s = *(const float2*)(Sin + si);
#pragma unroll 8
    for (int t = 0; t < TC; t++) {
        float2 l  = *(const float2*)(lp + (size_t)t * D_);
        float2 xv = *(const float2*)(xp + (size_t)t * D_);
        s.x = l.x * s.x + (1.f - l.x) * xv.x;
        s.y = l.y * s.y + (1.f - l.y) * xv.y;
        *(float2*)(lp + (size_t)t * D_) = s;   // read-before-write, same thread
    }
}

extern "C" void kernel_launch(void* const* d_in, const int* in_sizes, int n_in,
                              void* d_out, int out_size, void* d_ws, size_t ws_size,
                              hipStream_t stream) {
    const float* x    = (const float*)d_in[0];
    const float* W    = (const float*)d_in[1];
    const float* bias = (const float*)d_in[2];
    float* out = (float*)d_out;
    char* ws = (char*)d_ws;

    unsigned short* xT = (unsigned short*)ws;                       // 32 MiB  [B][D][K] bf16
    unsigned short* Wb = (unsigned short*)(ws + 33554432);          // 8 MiB   [K][K] bf16

    // Fused path needs Ac/Uc live DURING gemm (other WGs still read Wb/xT), so
    // they must sit in fresh ws after Wb: needs 40 MiB + 2 MiB = 44040192 B.
    const int fuse = (ws_size >= 44040192u) ? 1 : 0;
    float* Ac, * Uc;
    if (fuse) {
        Ac = (float*)(ws + 41943040);
        Uc = (float*)(ws + 41943040 + 1048576);
    } else {
        Ac = (float*)(ws + 33554432);                // overlay Wb (dead post-gemm)
        Uc = (float*)(ws + 33554432 + 1048576);
    }
    float* Sin = (float*)(ws + 33554432 + 2097152);  // overlay Wb tail (post-gemm only)

    conv_w<<<dim3(K_ * K_ / 4 / 256), 256, 0, stream>>>(W, Wb);
    conv_x_t<<<dim3(K_ / 64, D_ / 64, B_), 256, 0, stream>>>(x, xT);
    // lam goes into d_out; pass3 overwrites it in place with the final scan output
    gemm_sig<<<dim3(256), dim3(512), 0, stream>>>(Wb, xT, bias, x, out, Ac, Uc, fuse);
    if (!fuse)
        scan_pass1<<<dim3(B_ * NC * D_ / 2 / 256), 256, 0, stream>>>(out, x, Ac, Uc);
    scan_pass2<<<dim3(B_ * D_ / 64), 64, 0, stream>>>(Ac, Uc, Sin);
    scan_pass3<<<dim3(B_ * NC * D_ / 2 / 256), 256, 0, stream>>>(x, Sin, out);
}

// Round 3
// 237.050 us; speedup vs baseline: 1.1629x; 1.0017x over previous
//
#include <hip/hip_runtime.h>
#include <hip/hip_bf16.h>
#include <stdint.h>

#define B_ 8
#define K_ 2048
#define D_ 1024
#define NC 32
#define TC (K_ / NC)   // 64 timesteps per chunk

typedef float v4f __attribute__((ext_vector_type(4)));
typedef short v8s __attribute__((ext_vector_type(8)));

__device__ __forceinline__ unsigned short f2bf(float f) {
    __hip_bfloat16 h = __float2bfloat16(f);
    return *reinterpret_cast<unsigned short*>(&h);
}

__device__ __forceinline__ void async_ld16(const void* g, void* l) {
    __builtin_amdgcn_global_load_lds(
        (__attribute__((address_space(1))) void*)(void*)g,
        (__attribute__((address_space(3))) void*)l,
        16, 0, 0);
}

// ---------------- converter: W (fp32 [K][K]) -> bf16 [K][K] ----------------
__global__ void conv_w(const float* __restrict__ W, unsigned short* __restrict__ Wb) {
    int i = (blockIdx.x * 256 + threadIdx.x) * 4;
    float4 v = *(const float4*)(W + i);
    ushort4 o;
    o.x = f2bf(v.x); o.y = f2bf(v.y); o.z = f2bf(v.z); o.w = f2bf(v.w);
    *(ushort4*)(Wb + i) = o;
}

// ---------- converter+transpose: x fp32 [B][K][D] -> xT bf16 [B][D][K] ----------
__global__ void conv_x_t(const float* __restrict__ x, unsigned short* __restrict__ xT) {
    const int k0 = blockIdx.x * 64, d0 = blockIdx.y * 64, bb = blockIdx.z;
    __shared__ unsigned short tile[64][68];   // pad 68 to break bank alignment
    const int tid = threadIdx.x;
    const int tx = tid & 15, ty = tid >> 4;
    const float* xp = x + (size_t)bb * K_ * D_;
#pragma unroll
    for (int r = 0; r < 4; r++) {
        int row = ty + r * 16;
        float4 v = *(const float4*)(xp + (size_t)(k0 + row) * D_ + d0 + tx * 4);
        tile[row][tx * 4 + 0] = f2bf(v.x);
        tile[row][tx * 4 + 1] = f2bf(v.y);
        tile[row][tx * 4 + 2] = f2bf(v.z);
        tile[row][tx * 4 + 3] = f2bf(v.w);
    }
    __syncthreads();
    unsigned short* op = xT + (size_t)bb * D_ * K_;
#pragma unroll
    for (int r = 0; r < 4; r++) {
        int dcol = ty + r * 16;
        ushort4 u;
        u.x = tile[tx * 4 + 0][dcol];
        u.y = tile[tx * 4 + 1][dcol];
        u.z = tile[tx * 4 + 2][dcol];
        u.w = tile[tx * 4 + 3][dcol];
        *(ushort4*)(op + (size_t)(d0 + dcol) * K_ + k0 + tx * 4) = u;
    }
}

// ---------------- GEMM + bias + sigmoid (+ fused chunk-scan pass1) ----------------
// 256x256 tile, 8 waves (2M x 4N), 4-phase K-loop, counted vmcnt(4), XOR-swizzled
// LDS (bank conflicts measured 0). R3 changes:
//  - last K-iteration PEELED: no wasted tile-0 restage (-16 MB FETCH); peel ph2
//    ends with vmcnt(0) (at peel entry exactly the 4 kh1 halves are outstanding
//    and nothing new is issued, so the steady-state vmcnt(4) would not guarantee
//    their residency).
//  - epilogue scan: per chunk-group, all 64 x values are loaded into a fully
//    unrolled register array AFTER the sigmoid pass frees that cg's acc regs
//    (peak ~190 VGPR, still 2 waves/SIMD) -> the 64-step scan no longer eats
//    HBM latency per 8-unroll batch; tail is bandwidth-bound.
__launch_bounds__(512, 2)
__global__ void gemm_sig(const unsigned short* __restrict__ Wb,
                         const unsigned short* __restrict__ xT,
                         const float* __restrict__ bias,
                         const float* __restrict__ xf,
                         float* __restrict__ lam,
                         float* __restrict__ Ac,
                         float* __restrict__ Uc,
                         int fuse) {
    // [op][buf][kh][256 rows * 32 hw] : op0=A(W), op1=B(xT). 128 KiB total.
    __shared__ __align__(16) unsigned short smem_all[2][2][2][256 * 32];

    // XCD-chunked bijective swizzle (nwg=256): one batch b per XCD -> xT[b] ~ L2.
    const int bid = blockIdx.x;
    const int lid = (bid & 7) * 32 + (bid >> 3);
    const int bb = lid >> 5;          // batch
    const int tM = (lid >> 2) & 7;    // 8 M-tiles
    const int tN = lid & 3;           // 4 N-tiles

    const int tid = threadIdx.x;
    const int w = tid >> 6;           // wave 0..7
    const int lane = tid & 63;
    const int wm = w >> 2;            // 0..1  (M)
    const int wn = w & 3;             // 0..3  (N)
    const int quad = lane >> 4;
    const int l16 = lane & 15;

    const unsigned short* Ag = Wb + (size_t)(tM * 256) * K_;
    const unsigned short* Bg = xT + (size_t)bb * D_ * K_ + (size_t)(tN * 256) * K_;

    // staging lane constants: 1KB LDS block = 16 rows x 4 granules (16B each);
    // lane l holds granule gk = (l&3) ^ ((l>>3)&3) so LDS slot matches the
    // ds_read-side XOR (rule #21: gload_lds dest stays lane-linear; swizzle the
    // global source + the read address with the same involution).
    const int srow = lane >> 2;
    const int sgk8 = ((lane & 3) ^ ((lane >> 3) & 3)) * 8;   // halfword offset

    const int frg = (quad ^ ((l16 >> 1) & 3)) * 8;
    const int aoff = (wm * 128 + l16) * 32 + frg;
    const int boff = (wn * 64 + l16) * 32 + frg;

    v4f acc[8][4];
#pragma unroll
    for (int i = 0; i < 8; i++)
#pragma unroll
        for (int j = 0; j < 4; j++) acc[i][j] = (v4f)0.f;

#define STAGE_(op, bufi, kh, kk, Gp)                                                        \
    do {                                                                                    \
        async_ld16(Gp + (size_t)(w * 16 + srow) * K_ + (kk) + (kh) * 32 + sgk8,             \
                   &smem_all[op][bufi][kh][w * 512]);                                       \
        async_ld16(Gp + (size_t)((8 + w) * 16 + srow) * K_ + (kk) + (kh) * 32 + sgk8,       \
                   &smem_all[op][bufi][kh][(8 + w) * 512]);                                 \
    } while (0)

    // prologue: tile 0's 4 halves
    STAGE_(0, 0, 0, 0, Ag);
    STAGE_(1, 0, 0, 0, Bg);
    STAGE_(0, 0, 1, 0, Ag);
    STAGE_(1, 0, 1, 0, Bg);
    asm volatile("s_waitcnt vmcnt(4)");
    asm volatile("s_barrier" ::: "memory");

    v8s af[8], bf[2];

    const int NT = K_ / 64;           // 32
    for (int t = 0; t < NT - 1; ++t) {
        const int cur = t & 1, nxt = cur ^ 1;
        const int k1 = (t + 1) * 64;  // never wraps (t <= NT-2)

        // ---------------- phase 1: kh0, j01 ----------------
#pragma unroll
        for (int i = 0; i < 8; i++) af[i] = *(const v8s*)(&smem_all[0][cur][0][aoff + i * 512]);
        bf[0] = *(const v8s*)(&smem_all[1][cur][0][boff]);
        bf[1] = *(const v8s*)(&smem_all[1][cur][0][boff + 512]);
        STAGE_(0, nxt, 0, k1, Ag);
        asm volatile("s_barrier" ::: "memory");
        asm volatile("s_waitcnt lgkmcnt(0)");
        __builtin_amdgcn_sched_barrier(0);
        __builtin_amdgcn_s_setprio(1);
#pragma unroll
        for (int i = 0; i < 8; i++) {
            acc[i][0] = __builtin_amdgcn_mfma_f32_16x16x32_bf16(af[i], bf[0], acc[i][0], 0, 0, 0);
            acc[i][1] = __builtin_amdgcn_mfma_f32_16x16x32_bf16(af[i], bf[1], acc[i][1], 0, 0, 0);
        }
        __builtin_amdgcn_s_setprio(0);
        asm volatile("s_barrier" ::: "memory");

        // ---------------- phase 2: kh0, j23 ----------------
        bf[0] = *(const v8s*)(&smem_all[1][cur][0][boff + 2 * 512]);
        bf[1] = *(const v8s*)(&smem_all[1][cur][0][boff + 3 * 512]);
        STAGE_(1, nxt, 0, k1, Bg);
        asm volatile("s_barrier" ::: "memory");
        asm volatile("s_waitcnt lgkmcnt(0)");
        __builtin_amdgcn_sched_barrier(0);
        __builtin_amdgcn_s_setprio(1);
#pragma unroll
        for (int i = 0; i < 8; i++) {
            acc[i][2] = __builtin_amdgcn_mfma_f32_16x16x32_bf16(af[i], bf[0], acc[i][2], 0, 0, 0);
            acc[i][3] = __builtin_amdgcn_mfma_f32_16x16x32_bf16(af[i], bf[1], acc[i][3], 0, 0, 0);
        }
        __builtin_amdgcn_s_setprio(0);
        asm volatile("s_waitcnt vmcnt(4)");   // tile-t kh1 halves now resident
        asm volatile("s_barrier" ::: "memory");

        // ---------------- phase 3: kh1, j01 ----------------
#pragma unroll
        for (int i = 0; i < 8; i++) af[i] = *(const v8s*)(&smem_all[0][cur][1][aoff + i * 512]);
        bf[0] = *(const v8s*)(&smem_all[1][cur][1][boff]);
        bf[1] = *(const v8s*)(&smem_all[1][cur][1][boff + 512]);
        STAGE_(0, nxt, 1, k1, Ag);
        asm volatile("s_barrier" ::: "memory");
        asm volatile("s_waitcnt lgkmcnt(0)");
        __builtin_amdgcn_sched_barrier(0);
        __builtin_amdgcn_s_setprio(1);
#pragma unroll
        for (int i = 0; i < 8; i++) {
            acc[i][0] = __builtin_amdgcn_mfma_f32_16x16x32_bf16(af[i], bf[0], acc[i][0], 0, 0, 0);
            acc[i][1] = __builtin_amdgcn_mfma_f32_16x16x32_bf16(af[i], bf[1], acc[i][1], 0, 0, 0);
        }
        __builtin_amdgcn_s_setprio(0);
        asm volatile("s_barrier" ::: "memory");

        // ---------------- phase 4: kh1, j23 ----------------
        bf[0] = *(const v8s*)(&smem_all[1][cur][1][boff + 2 * 512]);
        bf[1] = *(const v8s*)(&smem_all[1][cur][1][boff + 3 * 512]);
        STAGE_(1, nxt, 1, k1, Bg);
        asm volatile("s_barrier" ::: "memory");
        asm volatile("s_waitcnt lgkmcnt(0)");
        __builtin_amdgcn_sched_barrier(0);
        __builtin_amdgcn_s_setprio(1);
#pragma unroll
        for (int i = 0; i < 8; i++) {
            acc[i][2] = __builtin_amdgcn_mfma_f32_16x16x32_bf16(af[i], bf[0], acc[i][2], 0, 0, 0);
            acc[i][3] = __builtin_amdgcn_mfma_f32_16x16x32_bf16(af[i], bf[1], acc[i][3], 0, 0, 0);
        }
        __builtin_amdgcn_s_setprio(0);
        asm volatile("s_waitcnt vmcnt(4)");   // tile-(t+1) kh0 halves now resident
        asm volatile("s_barrier" ::: "memory");
    }

    // ---------------- peeled last iteration (t = NT-1): no staging ----------------
    {
        const int cur = (NT - 1) & 1;
        // phase 1: kh0, j01
#pragma unroll
        for (int i = 0; i < 8; i++) af[i] = *(const v8s*)(&smem_all[0][cur][0][aoff + i * 512]);
        bf[0] = *(const v8s*)(&smem_all[1][cur][0][boff]);
        bf[1] = *(const v8s*)(&smem_all[1][cur][0][boff + 512]);
        asm volatile("s_barrier" ::: "memory");
        asm volatile("s_waitcnt lgkmcnt(0)");
        __builtin_amdgcn_sched_barrier(0);
        __builtin_amdgcn_s_setprio(1);
#pragma unroll
        for (int i = 0; i < 8; i++) {
            acc[i][0] = __builtin_amdgcn_mfma_f32_16x16x32_bf16(af[i], bf[0], acc[i][0], 0, 0, 0);
            acc[i][1] = __builtin_amdgcn_mfma_f32_16x16x32_bf16(af[i], bf[1], acc[i][1], 0, 0, 0);
        }
        __builtin_amdgcn_s_setprio(0);
        asm volatile("s_barrier" ::: "memory");

        // phase 2: kh0, j23
        bf[0] = *(const v8s*)(&smem_all[1][cur][0][boff + 2 * 512]);
        bf[1] = *(const v8s*)(&smem_all[1][cur][0][boff + 3 * 512]);
        asm volatile("s_barrier" ::: "memory");
        asm volatile("s_waitcnt lgkmcnt(0)");
        __builtin_amdgcn_sched_barrier(0);
        __builtin_amdgcn_s_setprio(1);
#pragma unroll
        for (int i = 0; i < 8; i++) {
            acc[i][2] = __builtin_amdgcn_mfma_f32_16x16x32_bf16(af[i], bf[0], acc[i][2], 0, 0, 0);
            acc[i][3] = __builtin_amdgcn_mfma_f32_16x16x32_bf16(af[i], bf[1], acc[i][3], 0, 0, 0);
        }
        __builtin_amdgcn_s_setprio(0);
        asm volatile("s_waitcnt vmcnt(0)");   // kh1 halves resident (nothing else in flight)
        asm volatile("s_barrier" ::: "memory");

        // phase 3: kh1, j01
#pragma unroll
        for (int i = 0; i < 8; i++) af[i] = *(const v8s*)(&smem_all[0][cur][1][aoff + i * 512]);
        bf[0] = *(const v8s*)(&smem_all[1][cur][1][boff]);
        bf[1] = *(const v8s*)(&smem_all[1][cur][1][boff + 512]);
        asm volatile("s_waitcnt lgkmcnt(0)");
        __builtin_amdgcn_sched_barrier(0);
        __builtin_amdgcn_s_setprio(1);
#pragma unroll
        for (int i = 0; i < 8; i++) {
            acc[i][0] = __builtin_amdgcn_mfma_f32_16x16x32_bf16(af[i], bf[0], acc[i][0], 0, 0, 0);
            acc[i][1] = __builtin_amdgcn_mfma_f32_16x16x32_bf16(af[i], bf[1], acc[i][1], 0, 0, 0);
        }
        __builtin_amdgcn_s_setprio(0);

        // phase 4: kh1, j23
        bf[0] = *(const v8s*)(&smem_all[1][cur][1][boff + 2 * 512]);
        bf[1] = *(const v8s*)(&smem_all[1][cur][1][boff + 3 * 512]);
        asm volatile("s_waitcnt lgkmcnt(0)");
        __builtin_amdgcn_sched_barrier(0);
        __builtin_amdgcn_s_setprio(1);
#pragma unroll
        for (int i = 0; i < 8; i++) {
            acc[i][2] = __builtin_amdgcn_mfma_f32_16x16x32_bf16(af[i], bf[0], acc[i][2], 0, 0, 0);
            acc[i][3] = __builtin_amdgcn_mfma_f32_16x16x32_bf16(af[i], bf[1], acc[i][3], 0, 0, 0);
        }
        __builtin_amdgcn_s_setprio(0);
        asm volatile("s_barrier" ::: "memory");   // all waves done with LDS -> scratch reuse safe
    }
#undef STAGE_

    float* out = lam + (size_t)bb * K_ * D_;
    const int dg = tN * 256 + wn * 64;       // wave col base in d

    if (fuse) {
        // wave-private 64x64 f32 scratch (16 KiB each, 8 waves = 128 KiB = all LDS)
        float* Swp = (float*)smem_all + w * 4096;
        const int swzw = quad * 16;          // write-side XOR: ((R>>2)&3)*16 == quad*16
#pragma unroll
        for (int cg = 0; cg < 2; cg++) {
            const int c = tM * 4 + wm * 2 + cg;   // global chunk id
            const int t0 = c * 64;
#pragma unroll
            for (int ii = 0; ii < 4; ii++) {
                int i = cg * 4 + ii;
                int rowb = t0 + ii * 16 + quad * 4;   // global t row base
                int Rb = ii * 16 + quad * 4;          // row within chunk
#pragma unroll
                for (int r = 0; r < 4; r++) {
                    float bt = bias[rowb + r];
#pragma unroll
                    for (int j = 0; j < 4; j++) {
                        int colc = j * 16 + l16;
                        float v = acc[i][j][r] + bt;
                        float sg = 1.f / (1.f + __expf(-v));
                        out[(size_t)(rowb + r) * D_ + dg + colc] = sg;
                        Swp[(Rb + r) * 64 + (colc ^ swzw)] = sg;
                    }
                }
            }
            // all 64 x values into registers (static indices -> VGPRs, rule #20);
            // issued after sigmoid frees this cg's acc quarter -> peak regs bounded.
            const float* xg = xf + ((size_t)bb * K_ + t0) * D_ + dg + lane;
            float xv[64];
#pragma unroll
            for (int tt = 0; tt < 64; tt++) xv[tt] = xg[(size_t)tt * D_];

            asm volatile("s_waitcnt lgkmcnt(0)");
            __builtin_amdgcn_sched_barrier(0);
            // sequential chunk scan: lane owns column d = dg + lane
            float A = 1.f, U = 0.f;
#pragma unroll
            for (int tt = 0; tt < 64; tt++) {
                float l = Swp[tt * 64 + (lane ^ (((tt >> 2) & 3) * 16))];
                A *= l;
                U = l * U + (1.f - l) * xv[tt];
            }
            size_t oi = ((size_t)bb * NC + c) * D_ + dg + lane;
            Ac[oi] = A;
            Uc[oi] = U;
            __builtin_amdgcn_sched_barrier(0);   // keep cg=1 writes below cg=0 reads
        }
    } else {
        // plain epilogue (fallback when ws too small for fused Ac/Uc placement)
#pragma unroll
        for (int i = 0; i < 8; i++) {
            int rowb = tM * 256 + wm * 128 + i * 16 + quad * 4;
#pragma unroll
            for (int r = 0; r < 4; r++) {
                float bt = bias[rowb + r];
#pragma unroll
                for (int j = 0; j < 4; j++) {
                    int col = tN * 256 + wn * 64 + j * 16 + l16;
                    float v = acc[i][j][r] + bt;
                    out[(size_t)(rowb + r) * D_ + col] = 1.f / (1.f + __expf(-v));
                }
            }
        }
    }
}

// -------- scan pass 1 (FALLBACK ONLY): per-(b,chunk,d2) affine composition --------
__global__ void scan_pass1(const float* __restrict__ lam, const float* __restrict__ x,
                           float* __restrict__ Ac, float* __restrict__ Uc) {
    int id = blockIdx.x * 256 + threadIdx.x;   // B*NC*D/2 = 131072
    int d2 = (id & 511) * 2;
    int c = (id >> 9) & (NC - 1);
    int bb = id >> 14;
    const float* lp = lam + ((size_t)bb * K_ + (size_t)c * TC) * D_ + d2;
    const float* xp = x   + ((size_t)bb * K_ + (size_t)c * TC) * D_ + d2;
    float2 A = make_float2(1.f, 1.f), U = make_float2(0.f, 0.f);
#pragma unroll 8
    for (int t = 0; t < TC; t++) {
        float2 l  = *(const float2*)(lp + (size_t)t * D_);
        float2 xv = *(const float2*)(xp + (size_t)t * D_);
        A.x *= l.x; A.y *= l.y;
        U.x = l.x * U.x + (1.f - l.x) * xv.x;
        U.y = l.y * U.y + (1.f - l.y) * xv.y;
    }
    size_t oi = ((size_t)bb * NC + c) * D_ + d2;
    *(float2*)(Ac + oi) = A;
    *(float2*)(Uc + oi) = U;
}

// -------- scan pass 3 (now also absorbs pass 2): prefix over chunks + replay --------
// Each block is one (b, chunk) x 256 d4-groups; the <=31-step chunk prefix is
// computed in-kernel from Ac/Uc (2 MB working set -> L2/L3-resident, ~free),
// removing the latency-bound pass2 kernel + its launch gap + the Sin buffer.
__global__ void scan_pass3(const float* __restrict__ x,
                           const float* __restrict__ Ac, const float* __restrict__ Uc,
                           float* __restrict__ lamout) {
    int id = blockIdx.x * 256 + threadIdx.x;   // B*NC*D/4 = 65536
    int d = (id & 255) * 4;
    int c = (id >> 8) & (NC - 1);
    int bb = id >> 13;
    // chunk-entry state: compose chunks 0..c-1 (uniform trip count per block)
    float4 s = make_float4(0.f, 0.f, 0.f, 0.f);
    for (int j = 0; j < c; j++) {
        size_t ji = ((size_t)bb * NC + j) * D_ + d;
        float4 A = *(const float4*)(Ac + ji);
        float4 U = *(const float4*)(Uc + ji);
        s.x = A.x * s.x + U.x;
        s.y = A.y * s.y + U.y;
        s.z = A.z * s.z + U.z;
        s.w = A.w * s.w + U.w;
    }
    float* lp = lamout + ((size_t)bb * K_ + (size_t)c * TC) * D_ + d;
    const float* xp = x + ((size_t)bb * K_ + (size_t)c * TC) * D_ + d;
#pragma unroll 8
    for (int t = 0; t < TC; t++) {
        float4 l  = *(const float4*)(lp + (size_t)t * D_);
        float4 xv = *(const float4*)(xp + (size_t)t * D_);
        s.x = l.x * s.x + (1.f - l.x) * xv.x;
        s.y = l.y * s.y + (1.f - l.y) * xv.y;
        s.z = l.z * s.z + (1.f - l.z) * xv.z;
        s.w = l.w * s.w + (1.f - l.w) * xv.w;
        *(float4*)(lp + (size_t)t * D_) = s;   // read-before-write, same thread
    }
}

extern "C" void kernel_launch(void* const* d_in, const int* in_sizes, int n_in,
                              void* d_out, int out_size, void* d_ws, size_t ws_size,
                              hipStream_t stream) {
    const float* x    = (const float*)d_in[0];
    const float* W    = (const float*)d_in[1];
    const float* bias = (const float*)d_in[2];
    float* out = (float*)d_out;
    char* ws = (char*)d_ws;

    unsigned short* xT = (unsigned short*)ws;                       // 32 MiB  [B][D][K] bf16
    unsigned short* Wb = (unsigned short*)(ws + 33554432);          // 8 MiB   [K][K] bf16

    // Fused path needs Ac/Uc live DURING gemm (other WGs still read Wb/xT), so
    // they must sit in fresh ws after Wb: needs 40 MiB + 2 MiB = 44040192 B.
    const int fuse = (ws_size >= 44040192u) ? 1 : 0;
    float* Ac, * Uc;
    if (fuse) {
        Ac = (float*)(ws + 41943040);
        Uc = (float*)(ws + 41943040 + 1048576);
    } else {
        Ac = (float*)(ws + 33554432);                // overlay Wb (dead post-gemm)
        Uc = (float*)(ws + 33554432 + 1048576);
    }

    conv_w<<<dim3(K_ * K_ / 4 / 256), 256, 0, stream>>>(W, Wb);
    conv_x_t<<<dim3(K_ / 64, D_ / 64, B_), 256, 0, stream>>>(x, xT);
    // lam goes into d_out; pass3 overwrites it in place with the final scan output
    gemm_sig<<<dim3(256), dim3(512), 0, stream>>>(Wb, xT, bias, x, out, Ac, Uc, fuse);
    if (!fuse)
        scan_pass1<<<dim3(B_ * NC * D_ / 2 / 256), 256, 0, stream>>>(out, x, Ac, Uc);
    scan_pass3<<<dim3(B_ * NC * D_ / 4 / 256), 256, 0, stream>>>(x, Ac, Uc, out);
}

// Round 4
// 236.468 us; speedup vs baseline: 1.1658x; 1.0025x over previous
//
#include <hip/hip_runtime.h>
#include <hip/hip_bf16.h>
#include <stdint.h>

#define B_ 8
#define K_ 2048
#define D_ 1024
#define NC 32
#define TC (K_ / NC)   // 64 timesteps per chunk

typedef float v4f __attribute__((ext_vector_type(4)));
typedef short v8s __attribute__((ext_vector_type(8)));

__device__ __forceinline__ unsigned short f2bf(float f) {
    __hip_bfloat16 h = __float2bfloat16(f);
    return *reinterpret_cast<unsigned short*>(&h);
}

__device__ __forceinline__ void async_ld16(const void* g, void* l) {
    __builtin_amdgcn_global_load_lds(
        (__attribute__((address_space(1))) void*)(void*)g,
        (__attribute__((address_space(3))) void*)l,
        16, 0, 0);
}

// ------- fused converters: blocks [0,4096) = W->bf16; [4096,8192) = x->xT -------
// (one launch instead of two; both parts are 256-thread memory-bound blocks)
__global__ void conv_all(const float* __restrict__ W, unsigned short* __restrict__ Wb,
                         const float* __restrict__ x, unsigned short* __restrict__ xT) {
    if (blockIdx.x < 4096) {
        int i = (blockIdx.x * 256 + threadIdx.x) * 4;
        float4 v = *(const float4*)(W + i);
        ushort4 o;
        o.x = f2bf(v.x); o.y = f2bf(v.y); o.z = f2bf(v.z); o.w = f2bf(v.w);
        *(ushort4*)(Wb + i) = o;
        return;
    }
    const int t = blockIdx.x - 4096;
    const int k0 = (t & 31) * 64, d0 = ((t >> 5) & 15) * 64, bb = t >> 9;
    __shared__ unsigned short tile[64][68];   // pad 68 to break bank alignment
    const int tid = threadIdx.x;
    const int tx = tid & 15, ty = tid >> 4;
    const float* xp = x + (size_t)bb * K_ * D_;
#pragma unroll
    for (int r = 0; r < 4; r++) {
        int row = ty + r * 16;
        float4 v = *(const float4*)(xp + (size_t)(k0 + row) * D_ + d0 + tx * 4);
        tile[row][tx * 4 + 0] = f2bf(v.x);
        tile[row][tx * 4 + 1] = f2bf(v.y);
        tile[row][tx * 4 + 2] = f2bf(v.z);
        tile[row][tx * 4 + 3] = f2bf(v.w);
    }
    __syncthreads();
    unsigned short* op = xT + (size_t)bb * D_ * K_;
#pragma unroll
    for (int r = 0; r < 4; r++) {
        int dcol = ty + r * 16;
        ushort4 u;
        u.x = tile[tx * 4 + 0][dcol];
        u.y = tile[tx * 4 + 1][dcol];
        u.z = tile[tx * 4 + 2][dcol];
        u.w = tile[tx * 4 + 3][dcol];
        *(ushort4*)(op + (size_t)(d0 + dcol) * K_ + k0 + tx * 4) = u;
    }
}

// ---------------- GEMM + bias + sigmoid (+ fused chunk-scan pass1) ----------------
// 256x256 tile, 8 waves (2M x 4N), 4-phase K-loop, counted vmcnt(4), XOR-swizzled
// LDS (bank conflicts measured 0). Last K-iteration peeled (no tile-0 restage).
// Epilogue = R2 form (streaming x reads, unroll 8): the R3 xv[64] register array
// SPILLED to scratch (gemm 85.5 -> 123.2 us, ~64 MB hidden scratch traffic) and
// is reverted here. Each WG tile covers 4 complete time-chunks x 256 d-cols; the
// per-chunk (A,U) scan runs in the epilogue off a wave-private 64x64 f32 LDS
// scratch (XOR-swizzled, conflict-free), x read straight from global (coalesced,
// exactly once chip-wide). Removes scan_pass1 (-128 MB of lam+x re-reads).
__launch_bounds__(512, 2)
__global__ void gemm_sig(const unsigned short* __restrict__ Wb,
                         const unsigned short* __restrict__ xT,
                         const float* __restrict__ bias,
                         const float* __restrict__ xf,
                         float* __restrict__ lam,
                         float* __restrict__ Ac,
                         float* __restrict__ Uc,
                         int fuse) {
    // [op][buf][kh][256 rows * 32 hw] : op0=A(W), op1=B(xT). 128 KiB total.
    __shared__ __align__(16) unsigned short smem_all[2][2][2][256 * 32];

    // XCD-chunked bijective swizzle (nwg=256): one batch b per XCD -> xT[b] ~ L2.
    const int bid = blockIdx.x;
    const int lid = (bid & 7) * 32 + (bid >> 3);
    const int bb = lid >> 5;          // batch
    const int tM = (lid >> 2) & 7;    // 8 M-tiles
    const int tN = lid & 3;           // 4 N-tiles

    const int tid = threadIdx.x;
    const int w = tid >> 6;           // wave 0..7
    const int lane = tid & 63;
    const int wm = w >> 2;            // 0..1  (M)
    const int wn = w & 3;             // 0..3  (N)
    const int quad = lane >> 4;
    const int l16 = lane & 15;

    const unsigned short* Ag = Wb + (size_t)(tM * 256) * K_;
    const unsigned short* Bg = xT + (size_t)bb * D_ * K_ + (size_t)(tN * 256) * K_;

    // staging lane constants: 1KB LDS block = 16 rows x 4 granules (16B each);
    // lane l holds granule gk = (l&3) ^ ((l>>3)&3) so LDS slot matches the
    // ds_read-side XOR (rule #21: gload_lds dest stays lane-linear; swizzle the
    // global source + the read address with the same involution).
    const int srow = lane >> 2;
    const int sgk8 = ((lane & 3) ^ ((lane >> 3) & 3)) * 8;   // halfword offset

    const int frg = (quad ^ ((l16 >> 1) & 3)) * 8;
    const int aoff = (wm * 128 + l16) * 32 + frg;
    const int boff = (wn * 64 + l16) * 32 + frg;

    v4f acc[8][4];
#pragma unroll
    for (int i = 0; i < 8; i++)
#pragma unroll
        for (int j = 0; j < 4; j++) acc[i][j] = (v4f)0.f;

#define STAGE_(op, bufi, kh, kk, Gp)                                                        \
    do {                                                                                    \
        async_ld16(Gp + (size_t)(w * 16 + srow) * K_ + (kk) + (kh) * 32 + sgk8,             \
                   &smem_all[op][bufi][kh][w * 512]);                                       \
        async_ld16(Gp + (size_t)((8 + w) * 16 + srow) * K_ + (kk) + (kh) * 32 + sgk8,       \
                   &smem_all[op][bufi][kh][(8 + w) * 512]);                                 \
    } while (0)

    // prologue: tile 0's 4 halves
    STAGE_(0, 0, 0, 0, Ag);
    STAGE_(1, 0, 0, 0, Bg);
    STAGE_(0, 0, 1, 0, Ag);
    STAGE_(1, 0, 1, 0, Bg);
    asm volatile("s_waitcnt vmcnt(4)");
    asm volatile("s_barrier" ::: "memory");

    v8s af[8], bf[2];

    const int NT = K_ / 64;           // 32
    for (int t = 0; t < NT - 1; ++t) {
        const int cur = t & 1, nxt = cur ^ 1;
        const int k1 = (t + 1) * 64;  // never wraps (t <= NT-2)

        // ---------------- phase 1: kh0, j01 ----------------
#pragma unroll
        for (int i = 0; i < 8; i++) af[i] = *(const v8s*)(&smem_all[0][cur][0][aoff + i * 512]);
        bf[0] = *(const v8s*)(&smem_all[1][cur][0][boff]);
        bf[1] = *(const v8s*)(&smem_all[1][cur][0][boff + 512]);
        STAGE_(0, nxt, 0, k1, Ag);
        asm volatile("s_barrier" ::: "memory");
        asm volatile("s_waitcnt lgkmcnt(0)");
        __builtin_amdgcn_sched_barrier(0);
        __builtin_amdgcn_s_setprio(1);
#pragma unroll
        for (int i = 0; i < 8; i++) {
            acc[i][0] = __builtin_amdgcn_mfma_f32_16x16x32_bf16(af[i], bf[0], acc[i][0], 0, 0, 0);
            acc[i][1] = __builtin_amdgcn_mfma_f32_16x16x32_bf16(af[i], bf[1], acc[i][1], 0, 0, 0);
        }
        __builtin_amdgcn_s_setprio(0);
        asm volatile("s_barrier" ::: "memory");

        // ---------------- phase 2: kh0, j23 ----------------
        bf[0] = *(const v8s*)(&smem_all[1][cur][0][boff + 2 * 512]);
        bf[1] = *(const v8s*)(&smem_all[1][cur][0][boff + 3 * 512]);
        STAGE_(1, nxt, 0, k1, Bg);
        asm volatile("s_barrier" ::: "memory");
        asm volatile("s_waitcnt lgkmcnt(0)");
        __builtin_amdgcn_sched_barrier(0);
        __builtin_amdgcn_s_setprio(1);
#pragma unroll
        for (int i = 0; i < 8; i++) {
            acc[i][2] = __builtin_amdgcn_mfma_f32_16x16x32_bf16(af[i], bf[0], acc[i][2], 0, 0, 0);
            acc[i][3] = __builtin_amdgcn_mfma_f32_16x16x32_bf16(af[i], bf[1], acc[i][3], 0, 0, 0);
        }
        __builtin_amdgcn_s_setprio(0);
        asm volatile("s_waitcnt vmcnt(4)");   // tile-t kh1 halves now resident
        asm volatile("s_barrier" ::: "memory");

        // ---------------- phase 3: kh1, j01 ----------------
#pragma unroll
        for (int i = 0; i < 8; i++) af[i] = *(const v8s*)(&smem_all[0][cur][1][aoff + i * 512]);
        bf[0] = *(const v8s*)(&smem_all[1][cur][1][boff]);
        bf[1] = *(const v8s*)(&smem_all[1][cur][1][boff + 512]);
        STAGE_(0, nxt, 1, k1, Ag);
        asm volatile("s_barrier" ::: "memory");
        asm volatile("s_waitcnt lgkmcnt(0)");
        __builtin_amdgcn_sched_barrier(0);
        __builtin_amdgcn_s_setprio(1);
#pragma unroll
        for (int i = 0; i < 8; i++) {
            acc[i][0] = __builtin_amdgcn_mfma_f32_16x16x32_bf16(af[i], bf[0], acc[i][0], 0, 0, 0);
            acc[i][1] = __builtin_amdgcn_mfma_f32_16x16x32_bf16(af[i], bf[1], acc[i][1], 0, 0, 0);
        }
        __builtin_amdgcn_s_setprio(0);
        asm volatile("s_barrier" ::: "memory");

        // ---------------- phase 4: kh1, j23 ----------------
        bf[0] = *(const v8s*)(&smem_all[1][cur][1][boff + 2 * 512]);
        bf[1] = *(const v8s*)(&smem_all[1][cur][1][boff + 3 * 512]);
        STAGE_(1, nxt, 1, k1, Bg);
        asm volatile("s_barrier" ::: "memory");
        asm volatile("s_waitcnt lgkmcnt(0)");
        __builtin_amdgcn_sched_barrier(0);
        __builtin_amdgcn_s_setprio(1);
#pragma unroll
        for (int i = 0; i < 8; i++) {
            acc[i][2] = __builtin_amdgcn_mfma_f32_16x16x32_bf16(af[i], bf[0], acc[i][2], 0, 0, 0);
            acc[i][3] = __builtin_amdgcn_mfma_f32_16x16x32_bf16(af[i], bf[1], acc[i][3], 0, 0, 0);
        }
        __builtin_amdgcn_s_setprio(0);
        asm volatile("s_waitcnt vmcnt(4)");   // tile-(t+1) kh0 halves now resident
        asm volatile("s_barrier" ::: "memory");
    }

    // ---------------- peeled last iteration (t = NT-1): no staging ----------------
    {
        const int cur = (NT - 1) & 1;
        // phase 1: kh0, j01
#pragma unroll
        for (int i = 0; i < 8; i++) af[i] = *(const v8s*)(&smem_all[0][cur][0][aoff + i * 512]);
        bf[0] = *(const v8s*)(&smem_all[1][cur][0][boff]);
        bf[1] = *(const v8s*)(&smem_all[1][cur][0][boff + 512]);
        asm volatile("s_barrier" ::: "memory");
        asm volatile("s_waitcnt lgkmcnt(0)");
        __builtin_amdgcn_sched_barrier(0);
        __builtin_amdgcn_s_setprio(1);
#pragma unroll
        for (int i = 0; i < 8; i++) {
            acc[i][0] = __builtin_amdgcn_mfma_f32_16x16x32_bf16(af[i], bf[0], acc[i][0], 0, 0, 0);
            acc[i][1] = __builtin_amdgcn_mfma_f32_16x16x32_bf16(af[i], bf[1], acc[i][1], 0, 0, 0);
        }
        __builtin_amdgcn_s_setprio(0);
        asm volatile("s_barrier" ::: "memory");

        // phase 2: kh0, j23
        bf[0] = *(const v8s*)(&smem_all[1][cur][0][boff + 2 * 512]);
        bf[1] = *(const v8s*)(&smem_all[1][cur][0][boff + 3 * 512]);
        asm volatile("s_barrier" ::: "memory");
        asm volatile("s_waitcnt lgkmcnt(0)");
        __builtin_amdgcn_sched_barrier(0);
        __builtin_amdgcn_s_setprio(1);
#pragma unroll
        for (int i = 0; i < 8; i++) {
            acc[i][2] = __builtin_amdgcn_mfma_f32_16x16x32_bf16(af[i], bf[0], acc[i][2], 0, 0, 0);
            acc[i][3] = __builtin_amdgcn_mfma_f32_16x16x32_bf16(af[i], bf[1], acc[i][3], 0, 0, 0);
        }
        __builtin_amdgcn_s_setprio(0);
        asm volatile("s_waitcnt vmcnt(0)");   // kh1 halves resident (nothing else in flight)
        asm volatile("s_barrier" ::: "memory");

        // phase 3: kh1, j01
#pragma unroll
        for (int i = 0; i < 8; i++) af[i] = *(const v8s*)(&smem_all[0][cur][1][aoff + i * 512]);
        bf[0] = *(const v8s*)(&smem_all[1][cur][1][boff]);
        bf[1] = *(const v8s*)(&smem_all[1][cur][1][boff + 512]);
        asm volatile("s_waitcnt lgkmcnt(0)");
        __builtin_amdgcn_sched_barrier(0);
        __builtin_amdgcn_s_setprio(1);
#pragma unroll
        for (int i = 0; i < 8; i++) {
            acc[i][0] = __builtin_amdgcn_mfma_f32_16x16x32_bf16(af[i], bf[0], acc[i][0], 0, 0, 0);
            acc[i][1] = __builtin_amdgcn_mfma_f32_16x16x32_bf16(af[i], bf[1], acc[i][1], 0, 0, 0);
        }
        __builtin_amdgcn_s_setprio(0);

        // phase 4: kh1, j23
        bf[0] = *(const v8s*)(&smem_all[1][cur][1][boff + 2 * 512]);
        bf[1] = *(const v8s*)(&smem_all[1][cur][1][boff + 3 * 512]);
        asm volatile("s_waitcnt lgkmcnt(0)");
        __builtin_amdgcn_sched_barrier(0);
        __builtin_amdgcn_s_setprio(1);
#pragma unroll
        for (int i = 0; i < 8; i++) {
            acc[i][2] = __builtin_amdgcn_mfma_f32_16x16x32_bf16(af[i], bf[0], acc[i][2], 0, 0, 0);
            acc[i][3] = __builtin_amdgcn_mfma_f32_16x16x32_bf16(af[i], bf[1], acc[i][3], 0, 0, 0);
        }
        __builtin_amdgcn_s_setprio(0);
        asm volatile("s_barrier" ::: "memory");   // all waves done with LDS -> scratch reuse safe
    }
#undef STAGE_

    float* out = lam + (size_t)bb * K_ * D_;
    const int dg = tN * 256 + wn * 64;       // wave col base in d

    if (fuse) {
        // wave-private 64x64 f32 scratch (16 KiB each, 8 waves = 128 KiB = all LDS)
        float* Swp = (float*)smem_all + w * 4096;
        const int swzw = quad * 16;          // write-side XOR: ((R>>2)&3)*16 == quad*16
#pragma unroll
        for (int cg = 0; cg < 2; cg++) {
            const int c = tM * 4 + wm * 2 + cg;   // global chunk id
            const int t0 = c * 64;
#pragma unroll
            for (int ii = 0; ii < 4; ii++) {
                int i = cg * 4 + ii;
                int rowb = t0 + ii * 16 + quad * 4;   // global t row base
                int Rb = ii * 16 + quad * 4;          // row within chunk
#pragma unroll
                for (int r = 0; r < 4; r++) {
                    float bt = bias[rowb + r];
#pragma unroll
                    for (int j = 0; j < 4; j++) {
                        int colc = j * 16 + l16;
                        float v = acc[i][j][r] + bt;
                        float sg = 1.f / (1.f + __expf(-v));
                        out[(size_t)(rowb + r) * D_ + dg + colc] = sg;
                        Swp[(Rb + r) * 64 + (colc ^ swzw)] = sg;
                    }
                }
            }
            asm volatile("s_waitcnt lgkmcnt(0)");
            __builtin_amdgcn_sched_barrier(0);
            // sequential chunk scan: lane owns column d = dg + lane; streaming x
            // reads (8 in flight via unroll) — proven form, no register blow-up.
            const float* xg = xf + ((size_t)bb * K_ + t0) * D_ + dg + lane;
            float A = 1.f, U = 0.f;
#pragma unroll 8
            for (int tt = 0; tt < 64; tt++) {
                float l = Swp[tt * 64 + (lane ^ (((tt >> 2) & 3) * 16))];
                float xv = xg[(size_t)tt * D_];
                A *= l;
                U = l * U + (1.f - l) * xv;
            }
            size_t oi = ((size_t)bb * NC + c) * D_ + dg + lane;
            Ac[oi] = A;
            Uc[oi] = U;
            __builtin_amdgcn_sched_barrier(0);   // keep cg=1 writes below cg=0 reads
        }
    } else {
        // plain epilogue (fallback when ws too small for fused Ac/Uc placement)
#pragma unroll
        for (int i = 0; i < 8; i++) {
            int rowb = tM * 256 + wm * 128 + i * 16 + quad * 4;
#pragma unroll
            for (int r = 0; r < 4; r++) {
                float bt = bias[rowb + r];
#pragma unroll
                for (int j = 0; j < 4; j++) {
                    int col = tN * 256 + wn * 64 + j * 16 + l16;
                    float v = acc[i][j][r] + bt;
                    out[(size_t)(rowb + r) * D_ + col] = 1.f / (1.f + __expf(-v));
                }
            }
        }
    }
}

// -------- scan pass 1 (FALLBACK ONLY): per-(b,chunk,d2) affine composition --------
__global__ void scan_pass1(const float* __restrict__ lam, const float* __restrict__ x,
                           float* __restrict__ Ac, float* __restrict__ Uc) {
    int id = blockIdx.x * 256 + threadIdx.x;   // B*NC*D/2 = 131072
    int d2 = (id & 511) * 2;
    int c = (id >> 9) & (NC - 1);
    int bb = id >> 14;
    const float* lp = lam + ((size_t)bb * K_ + (size_t)c * TC) * D_ + d2;
    const float* xp = x   + ((size_t)bb * K_ + (size_t)c * TC) * D_ + d2;
    float2 A = make_float2(1.f, 1.f), U = make_float2(0.f, 0.f);
#pragma unroll 8
    for (int t = 0; t < TC; t++) {
        float2 l  = *(const float2*)(lp + (size_t)t * D_);
        float2 xv = *(const float2*)(xp + (size_t)t * D_);
        A.x *= l.x; A.y *= l.y;
        U.x = l.x * U.x + (1.f - l.x) * xv.x;
        U.y = l.y * U.y + (1.f - l.y) * xv.y;
    }
    size_t oi = ((size_t)bb * NC + c) * D_ + d2;
    *(float2*)(Ac + oi) = A;
    *(float2*)(Uc + oi) = U;
}

// -------- scan pass 3 (also absorbs pass 2): prefix over chunks + replay --------
// Each block is one (b, chunk) x 256 d4-groups; the <=31-step chunk prefix is
// computed in-kernel from Ac/Uc (2 MB working set -> L2/L3-resident, ~free).
__global__ void scan_pass3(const float* __restrict__ x,
                           const float* __restrict__ Ac, const float* __restrict__ Uc,
                           float* __restrict__ lamout) {
    int id = blockIdx.x * 256 + threadIdx.x;   // B*NC*D/4 = 65536
    int d = (id & 255) * 4;
    int c = (id >> 8) & (NC - 1);
    int bb = id >> 13;
    // chunk-entry state: compose chunks 0..c-1 (uniform trip count per block)
    float4 s = make_float4(0.f, 0.f, 0.f, 0.f);
    for (int j = 0; j < c; j++) {
        size_t ji = ((size_t)bb * NC + j) * D_ + d;
        float4 A = *(const float4*)(Ac + ji);
        float4 U = *(const float4*)(Uc + ji);
        s.x = A.x * s.x + U.x;
        s.y = A.y * s.y + U.y;
        s.z = A.z * s.z + U.z;
        s.w = A.w * s.w + U.w;
    }
    float* lp = lamout + ((size_t)bb * K_ + (size_t)c * TC) * D_ + d;
    const float* xp = x + ((size_t)bb * K_ + (size_t)c * TC) * D_ + d;
#pragma unroll 8
    for (int t = 0; t < TC; t++) {
        float4 l  = *(const float4*)(lp + (size_t)t * D_);
        float4 xv = *(const float4*)(xp + (size_t)t * D_);
        s.x = l.x * s.x + (1.f - l.x) * xv.x;
        s.y = l.y * s.y + (1.f - l.y) * xv.y;
        s.z = l.z * s.z + (1.f - l.z) * xv.z;
        s.w = l.w * s.w + (1.f - l.w) * xv.w;
        *(float4*)(lp + (size_t)t * D_) = s;   // read-before-write, same thread
    }
}

extern "C" void kernel_launch(void* const* d_in, const int* in_sizes, int n_in,
                              void* d_out, int out_size, void* d_ws, size_t ws_size,
                              hipStream_t stream) {
    const float* x    = (const float*)d_in[0];
    const float* W    = (const float*)d_in[1];
    const float* bias = (const float*)d_in[2];
    float* out = (float*)d_out;
    char* ws = (char*)d_ws;

    unsigned short* xT = (unsigned short*)ws;                       // 32 MiB  [B][D][K] bf16
    unsigned short* Wb = (unsigned short*)(ws + 33554432);          // 8 MiB   [K][K] bf16

    // Fused path needs Ac/Uc live DURING gemm (other WGs still read Wb/xT), so
    // they must sit in fresh ws after Wb: needs 40 MiB + 2 MiB = 44040192 B.
    const int fuse = (ws_size >= 44040192u) ? 1 : 0;
    float* Ac, * Uc;
    if (fuse) {
        Ac = (float*)(ws + 41943040);
        Uc = (float*)(ws + 41943040 + 1048576);
    } else {
        Ac = (float*)(ws + 33554432);                // overlay Wb (dead post-gemm)
        Uc = (float*)(ws + 33554432 + 1048576);
    }

    conv_all<<<dim3(8192), 256, 0, stream>>>(W, Wb, x, xT);
    // lam goes into d_out; pass3 overwrites it in place with the final scan output
    gemm_sig<<<dim3(256), dim3(512), 0, stream>>>(Wb, xT, bias, x, out, Ac, Uc, fuse);
    if (!fuse)
        scan_pass1<<<dim3(B_ * NC * D_ / 2 / 256), 256, 0, stream>>>(out, x, Ac, Uc);
    scan_pass3<<<dim3(B_ * NC * D_ / 4 / 256), 256, 0, stream>>>(x, Ac, Uc, out);
}

// Round 5
// 234.439 us; speedup vs baseline: 1.1759x; 1.0087x over previous
//
#include <hip/hip_runtime.h>
#include <hip/hip_bf16.h>
#include <stdint.h>

#define B_ 8
#define K_ 2048
#define D_ 1024
#define NC 32
#define TC (K_ / NC)   // 64 timesteps per chunk

typedef float v4f __attribute__((ext_vector_type(4)));
typedef short v8s __attribute__((ext_vector_type(8)));

__device__ __forceinline__ unsigned short f2bf(float f) {
    __hip_bfloat16 h = __float2bfloat16(f);
    return *reinterpret_cast<unsigned short*>(&h);
}

__device__ __forceinline__ void async_ld16(const void* g, void* l) {
    __builtin_amdgcn_global_load_lds(
        (__attribute__((address_space(1))) void*)(void*)g,
        (__attribute__((address_space(3))) void*)l,
        16, 0, 0);
}

// ------- fused converters: blocks [0,4096) = W->bf16; [4096,8192) = x->xT -------
__global__ void conv_all(const float* __restrict__ W, unsigned short* __restrict__ Wb,
                         const float* __restrict__ x, unsigned short* __restrict__ xT) {
    if (blockIdx.x < 4096) {
        int i = (blockIdx.x * 256 + threadIdx.x) * 4;
        float4 v = *(const float4*)(W + i);
        ushort4 o;
        o.x = f2bf(v.x); o.y = f2bf(v.y); o.z = f2bf(v.z); o.w = f2bf(v.w);
        *(ushort4*)(Wb + i) = o;
        return;
    }
    const int t = blockIdx.x - 4096;
    const int k0 = (t & 31) * 64, d0 = ((t >> 5) & 15) * 64, bb = t >> 9;
    __shared__ unsigned short tile[64][68];   // pad 68 to break bank alignment
    const int tid = threadIdx.x;
    const int tx = tid & 15, ty = tid >> 4;
    const float* xp = x + (size_t)bb * K_ * D_;
#pragma unroll
    for (int r = 0; r < 4; r++) {
        int row = ty + r * 16;
        float4 v = *(const float4*)(xp + (size_t)(k0 + row) * D_ + d0 + tx * 4);
        tile[row][tx * 4 + 0] = f2bf(v.x);
        tile[row][tx * 4 + 1] = f2bf(v.y);
        tile[row][tx * 4 + 2] = f2bf(v.z);
        tile[row][tx * 4 + 3] = f2bf(v.w);
    }
    __syncthreads();
    unsigned short* op = xT + (size_t)bb * D_ * K_;
#pragma unroll
    for (int r = 0; r < 4; r++) {
        int dcol = ty + r * 16;
        ushort4 u;
        u.x = tile[tx * 4 + 0][dcol];
        u.y = tile[tx * 4 + 1][dcol];
        u.z = tile[tx * 4 + 2][dcol];
        u.w = tile[tx * 4 + 3][dcol];
        *(ushort4*)(op + (size_t)(d0 + dcol) * K_ + k0 + tx * 4) = u;
    }
}

// ---------------- GEMM + bias + sigmoid (+ fused chunk-scan pass1) ----------------
// 256x256 tile, 8 waves (2M x 4N), 4-phase K-loop, counted vmcnt(4), XOR-swizzled
// LDS (bank conflicts measured 0). Last K-iteration peeled. Epilogue: streaming x
// reads (R3's xv[64] register array spilled; reverted in R4). R5: scan unroll
// 8 -> 16 (halves exposed HBM-latency batches; +16 transient VGPR only).
__launch_bounds__(512, 2)
__global__ void gemm_sig(const unsigned short* __restrict__ Wb,
                         const unsigned short* __restrict__ xT,
                         const float* __restrict__ bias,
                         const float* __restrict__ xf,
                         float* __restrict__ lam,
                         float* __restrict__ Ac,
                         float* __restrict__ Uc,
                         int fuse) {
    // [op][buf][kh][256 rows * 32 hw] : op0=A(W), op1=B(xT). 128 KiB total.
    __shared__ __align__(16) unsigned short smem_all[2][2][2][256 * 32];

    // XCD-chunked bijective swizzle (nwg=256): one batch b per XCD -> xT[b] ~ L2.
    const int bid = blockIdx.x;
    const int lid = (bid & 7) * 32 + (bid >> 3);
    const int bb = lid >> 5;          // batch
    const int tM = (lid >> 2) & 7;    // 8 M-tiles
    const int tN = lid & 3;           // 4 N-tiles

    const int tid = threadIdx.x;
    const int w = tid >> 6;           // wave 0..7
    const int lane = tid & 63;
    const int wm = w >> 2;            // 0..1  (M)
    const int wn = w & 3;             // 0..3  (N)
    const int quad = lane >> 4;
    const int l16 = lane & 15;

    const unsigned short* Ag = Wb + (size_t)(tM * 256) * K_;
    const unsigned short* Bg = xT + (size_t)bb * D_ * K_ + (size_t)(tN * 256) * K_;

    // staging lane constants: 1KB LDS block = 16 rows x 4 granules (16B each);
    // lane l holds granule gk = (l&3) ^ ((l>>3)&3) so LDS slot matches the
    // ds_read-side XOR (rule #21).
    const int srow = lane >> 2;
    const int sgk8 = ((lane & 3) ^ ((lane >> 3) & 3)) * 8;   // halfword offset

    const int frg = (quad ^ ((l16 >> 1) & 3)) * 8;
    const int aoff = (wm * 128 + l16) * 32 + frg;
    const int boff = (wn * 64 + l16) * 32 + frg;

    v4f acc[8][4];
#pragma unroll
    for (int i = 0; i < 8; i++)
#pragma unroll
        for (int j = 0; j < 4; j++) acc[i][j] = (v4f)0.f;

#define STAGE_(op, bufi, kh, kk, Gp)                                                        \
    do {                                                                                    \
        async_ld16(Gp + (size_t)(w * 16 + srow) * K_ + (kk) + (kh) * 32 + sgk8,             \
                   &smem_all[op][bufi][kh][w * 512]);                                       \
        async_ld16(Gp + (size_t)((8 + w) * 16 + srow) * K_ + (kk) + (kh) * 32 + sgk8,       \
                   &smem_all[op][bufi][kh][(8 + w) * 512]);                                 \
    } while (0)

    // prologue: tile 0's 4 halves
    STAGE_(0, 0, 0, 0, Ag);
    STAGE_(1, 0, 0, 0, Bg);
    STAGE_(0, 0, 1, 0, Ag);
    STAGE_(1, 0, 1, 0, Bg);
    asm volatile("s_waitcnt vmcnt(4)");
    asm volatile("s_barrier" ::: "memory");

    v8s af[8], bf[2];

    const int NT = K_ / 64;           // 32
    for (int t = 0; t < NT - 1; ++t) {
        const int cur = t & 1, nxt = cur ^ 1;
        const int k1 = (t + 1) * 64;  // never wraps (t <= NT-2)

        // ---------------- phase 1: kh0, j01 ----------------
#pragma unroll
        for (int i = 0; i < 8; i++) af[i] = *(const v8s*)(&smem_all[0][cur][0][aoff + i * 512]);
        bf[0] = *(const v8s*)(&smem_all[1][cur][0][boff]);
        bf[1] = *(const v8s*)(&smem_all[1][cur][0][boff + 512]);
        STAGE_(0, nxt, 0, k1, Ag);
        asm volatile("s_barrier" ::: "memory");
        asm volatile("s_waitcnt lgkmcnt(0)");
        __builtin_amdgcn_sched_barrier(0);
        __builtin_amdgcn_s_setprio(1);
#pragma unroll
        for (int i = 0; i < 8; i++) {
            acc[i][0] = __builtin_amdgcn_mfma_f32_16x16x32_bf16(af[i], bf[0], acc[i][0], 0, 0, 0);
            acc[i][1] = __builtin_amdgcn_mfma_f32_16x16x32_bf16(af[i], bf[1], acc[i][1], 0, 0, 0);
        }
        __builtin_amdgcn_s_setprio(0);
        asm volatile("s_barrier" ::: "memory");

        // ---------------- phase 2: kh0, j23 ----------------
        bf[0] = *(const v8s*)(&smem_all[1][cur][0][boff + 2 * 512]);
        bf[1] = *(const v8s*)(&smem_all[1][cur][0][boff + 3 * 512]);
        STAGE_(1, nxt, 0, k1, Bg);
        asm volatile("s_barrier" ::: "memory");
        asm volatile("s_waitcnt lgkmcnt(0)");
        __builtin_amdgcn_sched_barrier(0);
        __builtin_amdgcn_s_setprio(1);
#pragma unroll
        for (int i = 0; i < 8; i++) {
            acc[i][2] = __builtin_amdgcn_mfma_f32_16x16x32_bf16(af[i], bf[0], acc[i][2], 0, 0, 0);
            acc[i][3] = __builtin_amdgcn_mfma_f32_16x16x32_bf16(af[i], bf[1], acc[i][3], 0, 0, 0);
        }
        __builtin_amdgcn_s_setprio(0);
        asm volatile("s_waitcnt vmcnt(4)");   // tile-t kh1 halves now resident
        asm volatile("s_barrier" ::: "memory");

        // ---------------- phase 3: kh1, j01 ----------------
#pragma unroll
        for (int i = 0; i < 8; i++) af[i] = *(const v8s*)(&smem_all[0][cur][1][aoff + i * 512]);
        bf[0] = *(const v8s*)(&smem_all[1][cur][1][boff]);
        bf[1] = *(const v8s*)(&smem_all[1][cur][1][boff + 512]);
        STAGE_(0, nxt, 1, k1, Ag);
        asm volatile("s_barrier" ::: "memory");
        asm volatile("s_waitcnt lgkmcnt(0)");
        __builtin_amdgcn_sched_barrier(0);
        __builtin_amdgcn_s_setprio(1);
#pragma unroll
        for (int i = 0; i < 8; i++) {
            acc[i][0] = __builtin_amdgcn_mfma_f32_16x16x32_bf16(af[i], bf[0], acc[i][0], 0, 0, 0);
            acc[i][1] = __builtin_amdgcn_mfma_f32_16x16x32_bf16(af[i], bf[1], acc[i][1], 0, 0, 0);
        }
        __builtin_amdgcn_s_setprio(0);
        asm volatile("s_barrier" ::: "memory");

        // ---------------- phase 4: kh1, j23 ----------------
        bf[0] = *(const v8s*)(&smem_all[1][cur][1][boff + 2 * 512]);
        bf[1] = *(const v8s*)(&smem_all[1][cur][1][boff + 3 * 512]);
        STAGE_(1, nxt, 1, k1, Bg);
        asm volatile("s_barrier" ::: "memory");
        asm volatile("s_waitcnt lgkmcnt(0)");
        __builtin_amdgcn_sched_barrier(0);
        __builtin_amdgcn_s_setprio(1);
#pragma unroll
        for (int i = 0; i < 8; i++) {
            acc[i][2] = __builtin_amdgcn_mfma_f32_16x16x32_bf16(af[i], bf[0], acc[i][2], 0, 0, 0);
            acc[i][3] = __builtin_amdgcn_mfma_f32_16x16x32_bf16(af[i], bf[1], acc[i][3], 0, 0, 0);
        }
        __builtin_amdgcn_s_setprio(0);
        asm volatile("s_waitcnt vmcnt(4)");   // tile-(t+1) kh0 halves now resident
        asm volatile("s_barrier" ::: "memory");
    }

    // ---------------- peeled last iteration (t = NT-1): no staging ----------------
    {
        const int cur = (NT - 1) & 1;
        // phase 1: kh0, j01
#pragma unroll
        for (int i = 0; i < 8; i++) af[i] = *(const v8s*)(&smem_all[0][cur][0][aoff + i * 512]);
        bf[0] = *(const v8s*)(&smem_all[1][cur][0][boff]);
        bf[1] = *(const v8s*)(&smem_all[1][cur][0][boff + 512]);
        asm volatile("s_barrier" ::: "memory");
        asm volatile("s_waitcnt lgkmcnt(0)");
        __builtin_amdgcn_sched_barrier(0);
        __builtin_amdgcn_s_setprio(1);
#pragma unroll
        for (int i = 0; i < 8; i++) {
            acc[i][0] = __builtin_amdgcn_mfma_f32_16x16x32_bf16(af[i], bf[0], acc[i][0], 0, 0, 0);
            acc[i][1] = __builtin_amdgcn_mfma_f32_16x16x32_bf16(af[i], bf[1], acc[i][1], 0, 0, 0);
        }
        __builtin_amdgcn_s_setprio(0);
        asm volatile("s_barrier" ::: "memory");

        // phase 2: kh0, j23
        bf[0] = *(const v8s*)(&smem_all[1][cur][0][boff + 2 * 512]);
        bf[1] = *(const v8s*)(&smem_all[1][cur][0][boff + 3 * 512]);
        asm volatile("s_barrier" ::: "memory");
        asm volatile("s_waitcnt lgkmcnt(0)");
        __builtin_amdgcn_sched_barrier(0);
        __builtin_amdgcn_s_setprio(1);
#pragma unroll
        for (int i = 0; i < 8; i++) {
            acc[i][2] = __builtin_amdgcn_mfma_f32_16x16x32_bf16(af[i], bf[0], acc[i][2], 0, 0, 0);
            acc[i][3] = __builtin_amdgcn_mfma_f32_16x16x32_bf16(af[i], bf[1], acc[i][3], 0, 0, 0);
        }
        __builtin_amdgcn_s_setprio(0);
        asm volatile("s_waitcnt vmcnt(0)");   // kh1 halves resident (nothing else in flight)
        asm volatile("s_barrier" ::: "memory");

        // phase 3: kh1, j01
#pragma unroll
        for (int i = 0; i < 8; i++) af[i] = *(const v8s*)(&smem_all[0][cur][1][aoff + i * 512]);
        bf[0] = *(const v8s*)(&smem_all[1][cur][1][boff]);
        bf[1] = *(const v8s*)(&smem_all[1][cur][1][boff + 512]);
        asm volatile("s_waitcnt lgkmcnt(0)");
        __builtin_amdgcn_sched_barrier(0);
        __builtin_amdgcn_s_setprio(1);
#pragma unroll
        for (int i = 0; i < 8; i++) {
            acc[i][0] = __builtin_amdgcn_mfma_f32_16x16x32_bf16(af[i], bf[0], acc[i][0], 0, 0, 0);
            acc[i][1] = __builtin_amdgcn_mfma_f32_16x16x32_bf16(af[i], bf[1], acc[i][1], 0, 0, 0);
        }
        __builtin_amdgcn_s_setprio(0);

        // phase 4: kh1, j23
        bf[0] = *(const v8s*)(&smem_all[1][cur][1][boff + 2 * 512]);
        bf[1] = *(const v8s*)(&smem_all[1][cur][1][boff + 3 * 512]);
        asm volatile("s_waitcnt lgkmcnt(0)");
        __builtin_amdgcn_sched_barrier(0);
        __builtin_amdgcn_s_setprio(1);
#pragma unroll
        for (int i = 0; i < 8; i++) {
            acc[i][2] = __builtin_amdgcn_mfma_f32_16x16x32_bf16(af[i], bf[0], acc[i][2], 0, 0, 0);
            acc[i][3] = __builtin_amdgcn_mfma_f32_16x16x32_bf16(af[i], bf[1], acc[i][3], 0, 0, 0);
        }
        __builtin_amdgcn_s_setprio(0);
        asm volatile("s_barrier" ::: "memory");   // all waves done with LDS -> scratch reuse safe
    }
#undef STAGE_

    float* out = lam + (size_t)bb * K_ * D_;
    const int dg = tN * 256 + wn * 64;       // wave col base in d

    if (fuse) {
        // wave-private 64x64 f32 scratch (16 KiB each, 8 waves = 128 KiB = all LDS)
        float* Swp = (float*)smem_all + w * 4096;
        const int swzw = quad * 16;          // write-side XOR: ((R>>2)&3)*16 == quad*16
#pragma unroll
        for (int cg = 0; cg < 2; cg++) {
            const int c = tM * 4 + wm * 2 + cg;   // global chunk id
            const int t0 = c * 64;
#pragma unroll
            for (int ii = 0; ii < 4; ii++) {
                int i = cg * 4 + ii;
                int rowb = t0 + ii * 16 + quad * 4;   // global t row base
                int Rb = ii * 16 + quad * 4;          // row within chunk
#pragma unroll
                for (int r = 0; r < 4; r++) {
                    float bt = bias[rowb + r];
#pragma unroll
                    for (int j = 0; j < 4; j++) {
                        int colc = j * 16 + l16;
                        float v = acc[i][j][r] + bt;
                        float sg = 1.f / (1.f + __expf(-v));
                        out[(size_t)(rowb + r) * D_ + dg + colc] = sg;
                        Swp[(Rb + r) * 64 + (colc ^ swzw)] = sg;
                    }
                }
            }
            asm volatile("s_waitcnt lgkmcnt(0)");
            __builtin_amdgcn_sched_barrier(0);
            // sequential chunk scan: lane owns column d = dg + lane; streaming x
            // reads, unroll 16 (16 loads in flight -> 4 latency exposures).
            const float* xg = xf + ((size_t)bb * K_ + t0) * D_ + dg + lane;
            float A = 1.f, U = 0.f;
#pragma unroll 16
            for (int tt = 0; tt < 64; tt++) {
                float l = Swp[tt * 64 + (lane ^ (((tt >> 2) & 3) * 16))];
                float xv = xg[(size_t)tt * D_];
                A *= l;
                U = l * U + (1.f - l) * xv;
            }
            size_t oi = ((size_t)bb * NC + c) * D_ + dg + lane;
            Ac[oi] = A;
            Uc[oi] = U;
            __builtin_amdgcn_sched_barrier(0);   // keep cg=1 writes below cg=0 reads
        }
    } else {
        // plain epilogue (fallback when ws too small for fused Ac/Uc placement)
#pragma unroll
        for (int i = 0; i < 8; i++) {
            int rowb = tM * 256 + wm * 128 + i * 16 + quad * 4;
#pragma unroll
            for (int r = 0; r < 4; r++) {
                float bt = bias[rowb + r];
#pragma unroll
                for (int j = 0; j < 4; j++) {
                    int col = tN * 256 + wn * 64 + j * 16 + l16;
                    float v = acc[i][j][r] + bt;
                    out[(size_t)(rowb + r) * D_ + col] = 1.f / (1.f + __expf(-v));
                }
            }
        }
    }
}

// -------- scan pass 1 (FALLBACK ONLY): per-(b,chunk,d2) affine composition --------
__global__ void scan_pass1(const float* __restrict__ lam, const float* __restrict__ x,
                           float* __restrict__ Ac, float* __restrict__ Uc) {
    int id = blockIdx.x * 256 + threadIdx.x;   // B*NC*D/2 = 131072
    int d2 = (id & 511) * 2;
    int c = (id >> 9) & (NC - 1);
    int bb = id >> 14;
    const float* lp = lam + ((size_t)bb * K_ + (size_t)c * TC) * D_ + d2;
    const float* xp = x   + ((size_t)bb * K_ + (size_t)c * TC) * D_ + d2;
    float2 A = make_float2(1.f, 1.f), U = make_float2(0.f, 0.f);
#pragma unroll 8
    for (int t = 0; t < TC; t++) {
        float2 l  = *(const float2*)(lp + (size_t)t * D_);
        float2 xv = *(const float2*)(xp + (size_t)t * D_);
        A.x *= l.x; A.y *= l.y;
        U.x = l.x * U.x + (1.f - l.x) * xv.x;
        U.y = l.y * U.y + (1.f - l.y) * xv.y;
    }
    size_t oi = ((size_t)bb * NC + c) * D_ + d2;
    *(float2*)(Ac + oi) = A;
    *(float2*)(Uc + oi) = U;
}

// -------- scan pass 3 (absorbs pass 2): prefix over chunks + replay --------
// R5: float2/lane, 512 blocks x 256 thr = 2 blocks/CU = 8 waves/CU (was 4):
// doubles the latency-hiding wave pool for this latency-limited stream
// (192 MB at ~2.3 TB/s observed). Nontemporal stores (output never re-read)
// keep L2 for the lam/x read streams. Prefix (<=31 steps) from Ac/Uc stays
// in-kernel (2 MB, L2/L3-resident).
__launch_bounds__(256)
__global__ void scan_pass3(const float* __restrict__ x,
                           const float* __restrict__ Ac, const float* __restrict__ Uc,
                           float* __restrict__ lamout) {
    int id = blockIdx.x * 256 + threadIdx.x;   // B*NC*D/2 = 131072
    int d = (id & 511) * 2;
    int c = (id >> 9) & (NC - 1);
    int bb = id >> 14;
    // chunk-entry state: compose chunks 0..c-1 (uniform trip count per block)
    float2 s = make_float2(0.f, 0.f);
    for (int j = 0; j < c; j++) {
        size_t ji = ((size_t)bb * NC + j) * D_ + d;
        float2 A = *(const float2*)(Ac + ji);
        float2 U = *(const float2*)(Uc + ji);
        s.x = A.x * s.x + U.x;
        s.y = A.y * s.y + U.y;
    }
    float* lp = lamout + ((size_t)bb * K_ + (size_t)c * TC) * D_ + d;
    const float* xp = x + ((size_t)bb * K_ + (size_t)c * TC) * D_ + d;
#pragma unroll 8
    for (int t = 0; t < TC; t++) {
        float2 l  = *(const float2*)(lp + (size_t)t * D_);
        float2 xv = *(const float2*)(xp + (size_t)t * D_);
        s.x = l.x * s.x + (1.f - l.x) * xv.x;
        s.y = l.y * s.y + (1.f - l.y) * xv.y;
        __builtin_nontemporal_store(s.x, lp + (size_t)t * D_);
        __builtin_nontemporal_store(s.y, lp + (size_t)t * D_ + 1);
    }
}

extern "C" void kernel_launch(void* const* d_in, const int* in_sizes, int n_in,
                              void* d_out, int out_size, void* d_ws, size_t ws_size,
                              hipStream_t stream) {
    const float* x    = (const float*)d_in[0];
    const float* W    = (const float*)d_in[1];
    const float* bias = (const float*)d_in[2];
    float* out = (float*)d_out;
    char* ws = (char*)d_ws;

    unsigned short* xT = (unsigned short*)ws;                       // 32 MiB  [B][D][K] bf16
    unsigned short* Wb = (unsigned short*)(ws + 33554432);          // 8 MiB   [K][K] bf16

    // Fused path needs Ac/Uc live DURING gemm (other WGs still read Wb/xT), so
    // they must sit in fresh ws after Wb: needs 40 MiB + 2 MiB = 44040192 B.
    const int fuse = (ws_size >= 44040192u) ? 1 : 0;
    float* Ac, * Uc;
    if (fuse) {
        Ac = (float*)(ws + 41943040);
        Uc = (float*)(ws + 41943040 + 1048576);
    } else {
        Ac = (float*)(ws + 33554432);                // overlay Wb (dead post-gemm)
        Uc = (float*)(ws + 33554432 + 1048576);
    }

    conv_all<<<dim3(8192), 256, 0, stream>>>(W, Wb, x, xT);
    // lam goes into d_out; pass3 overwrites it in place with the final scan output
    gemm_sig<<<dim3(256), dim3(512), 0, stream>>>(Wb, xT, bias, x, out, Ac, Uc, fuse);
    if (!fuse)
        scan_pass1<<<dim3(B_ * NC * D_ / 2 / 256), 256, 0, stream>>>(out, x, Ac, Uc);
    scan_pass3<<<dim3(B_ * NC * D_ / 2 / 256), 256, 0, stream>>>(x, Ac, Uc, out);
}